// Round 4
// baseline (484.251 us; speedup 1.0000x reference)
//
#include <hip/hip_runtime.h>
#include <hip/hip_bf16.h>

#define B_ 2
#define S_ 2048
#define D_ 1024
#define H_ 16
#define HD_ 64

typedef __attribute__((ext_vector_type(8))) short short8;
typedef __attribute__((ext_vector_type(4))) float float4v;

static __device__ inline float b2f(__hip_bfloat16 h) { return __bfloat162float(h); }

static __device__ inline short f2bs(float x) {
  __hip_bfloat16 h = __float2bfloat16(x);
  union { __hip_bfloat16 h; short s; } u; u.h = h; return u.s;
}
static __device__ inline float bs2f(short s) {
  union { short s; __hip_bfloat16 h; } u; u.s = s; return __bfloat162float(u.h);
}

// ---------------- Stage A: W fp32 [k][n] -> Wt bf16 [n][k] ----------------
__global__ __launch_bounds__(256) void transpose_w(
    const float* __restrict__ Wq, const float* __restrict__ Wk,
    __hip_bfloat16* __restrict__ Wqt, __hip_bfloat16* __restrict__ Wkt) {
  const float* W = blockIdx.z ? Wk : Wq;
  __hip_bfloat16* Wt = blockIdx.z ? Wkt : Wqt;
  __shared__ float t[64][65];
  const int n0 = blockIdx.x * 64, k0 = blockIdx.y * 64;
  const int c = threadIdx.x & 63, r0 = threadIdx.x >> 6;
  for (int i = 0; i < 16; ++i) {
    const int r = i * 4 + r0;
    t[c][r] = W[(size_t)(k0 + r) * D_ + n0 + c];  // t[n-local][k-local]
  }
  __syncthreads();
  for (int i = 0; i < 16; ++i) {
    const int rr = i * 4 + r0;
    Wt[(size_t)(n0 + rr) * D_ + k0 + c] = __float2bfloat16(t[rr][c]);
  }
}

// ---------------- Stage B: fused-bias GEMM, z=0 -> q, z=1 -> k ----------------
// C[m][n] = sum_k A[m][k]*W[k][n] + bias[n]; A fp32 [4096][1024], Wt bf16 [n][k]
__global__ __launch_bounds__(256) void gemm_qk(
    const float* __restrict__ A,
    const __hip_bfloat16* __restrict__ Wqt, const __hip_bfloat16* __restrict__ Wkt,
    const float* __restrict__ bq, const float* __restrict__ bk,
    __hip_bfloat16* __restrict__ outq, __hip_bfloat16* __restrict__ outk) {
  const __hip_bfloat16* Wt = blockIdx.z ? Wkt : Wqt;
  const float* bias = blockIdx.z ? bk : bq;
  __hip_bfloat16* out = blockIdx.z ? outk : outq;
  const int m0 = blockIdx.y * 128, n0 = blockIdx.x * 128;
  __shared__ __hip_bfloat16 As[128 * 32];  // [m][k], rows of 32
  __shared__ __hip_bfloat16 Bs[128 * 32];  // [n][k], rows of 32
  const int tid = threadIdx.x, wid = tid >> 6, lane = tid & 63;
  const int wm = (wid >> 1) * 64, wn = (wid & 1) * 64;
  const int l15 = lane & 15, l4 = lane >> 4;
  float4v zz = {0.f, 0.f, 0.f, 0.f};
  float4v acc[4][4];
  for (int i = 0; i < 4; ++i)
    for (int j = 0; j < 4; ++j) acc[i][j] = zz;
  // lane's staging element offset: wid*1024 + 8*lane  <->  row=wid*32+lane/4, k8=(lane&3)*8
  const int lrow = wid * 32 + (lane >> 2);
  const int lk8 = (lane & 3) * 8;
  for (int kb = 0; kb < 32; ++kb) {
    const int kc = kb * 32 + lk8;
    const float* pa0 = A + (size_t)(m0 + lrow) * D_ + kc;
    const float* pa1 = A + (size_t)(m0 + lrow + 16) * D_ + kc;
    const float4v a0l = ((const float4v*)pa0)[0], a0h = ((const float4v*)pa0)[1];
    const float4v a1l = ((const float4v*)pa1)[0], a1h = ((const float4v*)pa1)[1];
    const short8 w0 = *(const short8*)(Wt + (size_t)(n0 + lrow) * D_ + kc);
    const short8 w1 = *(const short8*)(Wt + (size_t)(n0 + lrow + 16) * D_ + kc);
    short8 a0, a1;
    for (int j = 0; j < 4; ++j) {
      a0[j] = f2bs(a0l[j]); a0[4 + j] = f2bs(a0h[j]);
      a1[j] = f2bs(a1l[j]); a1[4 + j] = f2bs(a1h[j]);
    }
    __syncthreads();  // prev iteration's frag reads done
    *(short8*)(As + wid * 1024 + 8 * lane) = a0;
    *(short8*)(As + wid * 1024 + 512 + 8 * lane) = a1;
    *(short8*)(Bs + wid * 1024 + 8 * lane) = w0;
    *(short8*)(Bs + wid * 1024 + 512 + 8 * lane) = w1;
    __syncthreads();  // stores visible
    short8 af[4], bf[4];
    const int fo = l4 * 8;
    for (int rt = 0; rt < 4; ++rt)
      af[rt] = *(const short8*)(As + (wm + rt * 16 + l15) * 32 + fo);
    for (int ct = 0; ct < 4; ++ct)
      bf[ct] = *(const short8*)(Bs + (wn + ct * 16 + l15) * 32 + fo);
    for (int rt = 0; rt < 4; ++rt)
      for (int ct = 0; ct < 4; ++ct)
        acc[rt][ct] = __builtin_amdgcn_mfma_f32_16x16x32_bf16(af[rt], bf[ct], acc[rt][ct], 0, 0, 0);
  }
  float bv[4];
  for (int ct = 0; ct < 4; ++ct) bv[ct] = bias[n0 + wn + ct * 16 + l15];
  for (int rt = 0; rt < 4; ++rt)
    for (int ct = 0; ct < 4; ++ct) {
      const int col = n0 + wn + ct * 16 + l15;
      for (int r = 0; r < 4; ++r) {
        const int row = m0 + wm + rt * 16 + l4 * 4 + r;
        out[(size_t)row * D_ + col] = __float2bfloat16(acc[rt][ct][r] + bv[ct]);
      }
    }
}

// ------- Stage C: k <- softplus(k) (in place); vT[b,h,d,s] = q + k -------
__global__ __launch_bounds__(256) void prep(
    const __hip_bfloat16* __restrict__ qb, __hip_bfloat16* __restrict__ kb,
    __hip_bfloat16* __restrict__ vT) {
  __shared__ float vt[64][65];
  const int s0 = blockIdx.x * 64, h = blockIdx.y, b = blockIdx.z;
  const int d = threadIdx.x & 63, r0 = threadIdx.x >> 6;
  for (int i = 0; i < 16; ++i) {
    const int sl = i * 4 + r0;
    const size_t idx = (size_t)(b * S_ + s0 + sl) * D_ + h * HD_ + d;
    const float qv = b2f(qb[idx]);
    const float kv = b2f(kb[idx]);
    const float sp = (kv > 15.f) ? kv : log1pf(__expf(kv));  // -logsigmoid(-k) = softplus(k)
    kb[idx] = __float2bfloat16(sp);  // same thread read-then-write: safe
    vt[d][sl] = qv + kv;
  }
  __syncthreads();
  for (int i = 0; i < 16; ++i) {
    const int dd = i * 4 + r0;
    vT[(size_t)((b * H_ + h) * HD_ + dd) * S_ + s0 + d] = __float2bfloat16(vt[dd][d]);
  }
}

// ---------------- Stage D: attention ----------------
// block = (b, h, 16-query tile); 16 waves. Scores row [16][2048] resident in LDS.
// Output is fp32 (reference output dtype).
__global__ __launch_bounds__(1024) void attn(
    const __hip_bfloat16* __restrict__ qb, const __hip_bfloat16* __restrict__ ktb,
    const __hip_bfloat16* __restrict__ vT, const int* __restrict__ mask,
    float* __restrict__ out) {
  constexpr int S2 = 2052;  // +4 pad
  __shared__ float sc[16 * S2];  // 131,328 B (gfx950: 160KB/WG)
  __shared__ float inv_l[16];
  const int q0 = blockIdx.x * 16, h = blockIdx.y, b = blockIdx.z;
  const int tid = threadIdx.x, wid = tid >> 6, lane = tid & 63;
  const int l15 = lane & 15, l4 = lane >> 4;
  const __hip_bfloat16* qh = qb + (size_t)b * S_ * D_ + h * HD_;
  const __hip_bfloat16* kh = ktb + (size_t)b * S_ * D_ + h * HD_;
  const __hip_bfloat16* vh = vT + (size_t)(b * H_ + h) * HD_ * S_;
  const float4v zz = {0.f, 0.f, 0.f, 0.f};
  // ---- QK^T: wave w covers keys [128w, 128w+128) ----
  const short8 aq0 = *(const short8*)(qh + (size_t)(q0 + l15) * D_ + l4 * 8);
  const short8 aq1 = *(const short8*)(qh + (size_t)(q0 + l15) * D_ + 32 + l4 * 8);
  for (int t = 0; t < 8; ++t) {
    const int k0 = wid * 128 + t * 16;
    const short8 b0 = *(const short8*)(kh + (size_t)(k0 + l15) * D_ + l4 * 8);
    const short8 b1 = *(const short8*)(kh + (size_t)(k0 + l15) * D_ + 32 + l4 * 8);
    float4v c = zz;
    c = __builtin_amdgcn_mfma_f32_16x16x32_bf16(aq0, b0, c, 0, 0, 0);
    c = __builtin_amdgcn_mfma_f32_16x16x32_bf16(aq1, b1, c, 0, 0, 0);
    for (int r = 0; r < 4; ++r)
      sc[(l4 * 4 + r) * S2 + k0 + l15] = c[r];
  }
  __syncthreads();
  // ---- softmax: wave `wid` owns query-row `wid`; masked row -> exact uniform ----
  {
    const int row = wid;
    const bool masked = (mask[b * S_ + q0 + row] == 0);
    float* srow = sc + row * S2;
    float mx = -1e30f;
    for (int i = lane; i < S_; i += 64) {
      const float x = masked ? 0.f : srow[i] * 0.125f;  // /sqrt(64)
      mx = fmaxf(mx, x);
    }
    for (int o = 32; o; o >>= 1) mx = fmaxf(mx, __shfl_xor(mx, o));
    float sum = 0.f;
    for (int i = lane; i < S_; i += 64) {
      const float x = masked ? 0.f : srow[i] * 0.125f;
      const float p = __expf(x - mx);
      srow[i] = p;  // unnormalized; normalized at the final reduction
      sum += p;
    }
    for (int o = 32; o; o >>= 1) sum += __shfl_xor(sum, o);
    if (lane == 0) inv_l[row] = 1.f / sum;
  }
  __syncthreads();
  // ---- PV: wave w covers keys [128w, 128w+128); split-precision P (hi+lo bf16) ----
  float4v oacc[4] = {zz, zz, zz, zz};
  for (int ks = 0; ks < 4; ++ks) {
    const int kk = wid * 128 + ks * 32 + l4 * 8;
    const float* prow = sc + l15 * S2 + kk;
    const float4v p0 = *(const float4v*)prow;
    const float4v p1 = *(const float4v*)(prow + 4);
    short8 af, al;
    for (int j = 0; j < 4; ++j) {
      af[j] = f2bs(p0[j]);           al[j] = f2bs(p0[j] - bs2f(af[j]));
      af[4 + j] = f2bs(p1[j]);       al[4 + j] = f2bs(p1[j] - bs2f(af[4 + j]));
    }
    for (int nt = 0; nt < 4; ++nt) {
      const short8 bv = *(const short8*)(vh + (size_t)(nt * 16 + l15) * S_ + kk);
      oacc[nt] = __builtin_amdgcn_mfma_f32_16x16x32_bf16(af, bv, oacc[nt], 0, 0, 0);
      oacc[nt] = __builtin_amdgcn_mfma_f32_16x16x32_bf16(al, bv, oacc[nt], 0, 0, 0);
    }
  }
  __syncthreads();  // all PV reads of sc done -> safe to overlay reduction buffer
  for (int nt = 0; nt < 4; ++nt)
    for (int r = 0; r < 4; ++r)
      sc[(wid * 16 + l4 * 4 + r) * 65 + nt * 16 + l15] = oacc[nt][r];
  __syncthreads();
  const int q = tid >> 6, dd = tid & 63;
  float s = 0.f;
  for (int w = 0; w < 16; ++w) s += sc[(w * 16 + q) * 65 + dd];
  s *= inv_l[q];
  out[(size_t)(b * S_ + q0 + q) * D_ + h * HD_ + dd] = s;
}

extern "C" void kernel_launch(void* const* d_in, const int* in_sizes, int n_in,
                              void* d_out, int out_size, void* d_ws, size_t ws_size,
                              hipStream_t stream) {
  const float* hs = (const float*)d_in[0];
  const int* mask = (const int*)d_in[1];
  const float* Wq = (const float*)d_in[2];
  const float* bq = (const float*)d_in[3];
  const float* Wk = (const float*)d_in[4];
  const float* bk = (const float*)d_in[5];
  float* out = (float*)d_out;  // reference output dtype is float32
  char* ws = (char*)d_ws;
  const size_t MB = 1u << 20;
  __hip_bfloat16* q_b = (__hip_bfloat16*)(ws + 0 * MB);   // [B,S,D] bf16, 8MB
  __hip_bfloat16* k_b = (__hip_bfloat16*)(ws + 8 * MB);   // k then kt in-place, 8MB
  __hip_bfloat16* vT  = (__hip_bfloat16*)(ws + 16 * MB);  // [B,H,HD,S] 8MB
  __hip_bfloat16* Wqt = (__hip_bfloat16*)(ws + 24 * MB);  // 2MB
  __hip_bfloat16* Wkt = (__hip_bfloat16*)(ws + 26 * MB);  // 2MB

  transpose_w<<<dim3(16, 16, 2), 256, 0, stream>>>(Wq, Wk, Wqt, Wkt);
  gemm_qk<<<dim3(8, 32, 2), 256, 0, stream>>>(hs, Wqt, Wkt, bq, bk, q_b, k_b);
  prep<<<dim3(32, 16, 2), 256, 0, stream>>>(q_b, k_b, vT);
  attn<<<dim3(128, 16, 2), 1024, 0, stream>>>(q_b, k_b, vT, mask, out);
}

// Round 5
// 301.600 us; speedup vs baseline: 1.6056x; 1.6056x over previous
//
#include <hip/hip_runtime.h>
#include <hip/hip_bf16.h>

#define B_ 2
#define S_ 2048
#define D_ 1024
#define H_ 16
#define HD_ 64

typedef __attribute__((ext_vector_type(8))) short short8;
typedef __attribute__((ext_vector_type(4))) float float4v;

static __device__ inline float b2f(__hip_bfloat16 h) { return __bfloat162float(h); }

static __device__ inline short f2bs(float x) {
  __hip_bfloat16 h = __float2bfloat16(x);
  union { __hip_bfloat16 h; short s; } u; u.h = h; return u.s;
}
static __device__ inline float bs2f(short s) {
  union { short s; __hip_bfloat16 h; } u; u.s = s; return __bfloat162float(u.h);
}

// ---------------- Stage A: W fp32 [k][n] -> Wt bf16 [n][k] ----------------
__global__ __launch_bounds__(256) void transpose_w(
    const float* __restrict__ Wq, const float* __restrict__ Wk,
    __hip_bfloat16* __restrict__ Wqt, __hip_bfloat16* __restrict__ Wkt) {
  const float* W = blockIdx.z ? Wk : Wq;
  __hip_bfloat16* Wt = blockIdx.z ? Wkt : Wqt;
  __shared__ float t[64][65];
  const int n0 = blockIdx.x * 64, k0 = blockIdx.y * 64;
  const int c = threadIdx.x & 63, r0 = threadIdx.x >> 6;
  for (int i = 0; i < 16; ++i) {
    const int r = i * 4 + r0;
    t[c][r] = W[(size_t)(k0 + r) * D_ + n0 + c];  // t[n-local][k-local]
  }
  __syncthreads();
  for (int i = 0; i < 16; ++i) {
    const int rr = i * 4 + r0;
    Wt[(size_t)(n0 + rr) * D_ + k0 + c] = __float2bfloat16(t[rr][c]);
  }
}

// ---------------- Stage B: fused-bias GEMM, z=0 -> q, z=1 -> k ----------------
__global__ __launch_bounds__(256) void gemm_qk(
    const float* __restrict__ A,
    const __hip_bfloat16* __restrict__ Wqt, const __hip_bfloat16* __restrict__ Wkt,
    const float* __restrict__ bq, const float* __restrict__ bk,
    __hip_bfloat16* __restrict__ outq, __hip_bfloat16* __restrict__ outk) {
  const __hip_bfloat16* Wt = blockIdx.z ? Wkt : Wqt;
  const float* bias = blockIdx.z ? bk : bq;
  __hip_bfloat16* out = blockIdx.z ? outk : outq;
  const int m0 = blockIdx.y * 128, n0 = blockIdx.x * 128;
  __shared__ __hip_bfloat16 As[128 * 32];  // [m][k], rows of 32
  __shared__ __hip_bfloat16 Bs[128 * 32];  // [n][k], rows of 32
  const int tid = threadIdx.x, wid = tid >> 6, lane = tid & 63;
  const int wm = (wid >> 1) * 64, wn = (wid & 1) * 64;
  const int l15 = lane & 15, l4 = lane >> 4;
  float4v zz = {0.f, 0.f, 0.f, 0.f};
  float4v acc[4][4];
  for (int i = 0; i < 4; ++i)
    for (int j = 0; j < 4; ++j) acc[i][j] = zz;
  const int lrow = wid * 32 + (lane >> 2);
  const int lk8 = (lane & 3) * 8;
  for (int kb = 0; kb < 32; ++kb) {
    const int kc = kb * 32 + lk8;
    const float* pa0 = A + (size_t)(m0 + lrow) * D_ + kc;
    const float* pa1 = A + (size_t)(m0 + lrow + 16) * D_ + kc;
    const float4v a0l = ((const float4v*)pa0)[0], a0h = ((const float4v*)pa0)[1];
    const float4v a1l = ((const float4v*)pa1)[0], a1h = ((const float4v*)pa1)[1];
    const short8 w0 = *(const short8*)(Wt + (size_t)(n0 + lrow) * D_ + kc);
    const short8 w1 = *(const short8*)(Wt + (size_t)(n0 + lrow + 16) * D_ + kc);
    short8 a0, a1;
    for (int j = 0; j < 4; ++j) {
      a0[j] = f2bs(a0l[j]); a0[4 + j] = f2bs(a0h[j]);
      a1[j] = f2bs(a1l[j]); a1[4 + j] = f2bs(a1h[j]);
    }
    __syncthreads();
    *(short8*)(As + wid * 1024 + 8 * lane) = a0;
    *(short8*)(As + wid * 1024 + 512 + 8 * lane) = a1;
    *(short8*)(Bs + wid * 1024 + 8 * lane) = w0;
    *(short8*)(Bs + wid * 1024 + 512 + 8 * lane) = w1;
    __syncthreads();
    short8 af[4], bf[4];
    const int fo = l4 * 8;
    for (int rt = 0; rt < 4; ++rt)
      af[rt] = *(const short8*)(As + (wm + rt * 16 + l15) * 32 + fo);
    for (int ct = 0; ct < 4; ++ct)
      bf[ct] = *(const short8*)(Bs + (wn + ct * 16 + l15) * 32 + fo);
    for (int rt = 0; rt < 4; ++rt)
      for (int ct = 0; ct < 4; ++ct)
        acc[rt][ct] = __builtin_amdgcn_mfma_f32_16x16x32_bf16(af[rt], bf[ct], acc[rt][ct], 0, 0, 0);
  }
  float bv[4];
  for (int ct = 0; ct < 4; ++ct) bv[ct] = bias[n0 + wn + ct * 16 + l15];
  for (int rt = 0; rt < 4; ++rt)
    for (int ct = 0; ct < 4; ++ct) {
      const int col = n0 + wn + ct * 16 + l15;
      for (int r = 0; r < 4; ++r) {
        const int row = m0 + wm + rt * 16 + l4 * 4 + r;
        out[(size_t)row * D_ + col] = __float2bfloat16(acc[rt][ct][r] + bv[ct]);
      }
    }
}

// ------- Stage C: k <- softplus(k) (in place); vT[b,h,d,s] = q + k -------
__global__ __launch_bounds__(256) void prep(
    const __hip_bfloat16* __restrict__ qb, __hip_bfloat16* __restrict__ kb,
    __hip_bfloat16* __restrict__ vT) {
  __shared__ float vt[64][65];
  const int s0 = blockIdx.x * 64, h = blockIdx.y, b = blockIdx.z;
  const int d = threadIdx.x & 63, r0 = threadIdx.x >> 6;
  for (int i = 0; i < 16; ++i) {
    const int sl = i * 4 + r0;
    const size_t idx = (size_t)(b * S_ + s0 + sl) * D_ + h * HD_ + d;
    const float qv = b2f(qb[idx]);
    const float kv = b2f(kb[idx]);
    const float sp = (kv > 15.f) ? kv : log1pf(__expf(kv));  // softplus(k)
    kb[idx] = __float2bfloat16(sp);
    vt[d][sl] = qv + kv;
  }
  __syncthreads();
  for (int i = 0; i < 16; ++i) {
    const int dd = i * 4 + r0;
    vT[(size_t)((b * H_ + h) * HD_ + dd) * S_ + s0 + d] = __float2bfloat16(vt[dd][d]);
  }
}

// ---------------- Stage D: flash attention ----------------
// block = 256 thr (4 waves), 64 queries/block (16/wave), online softmax over
// 32 chunks of 64 keys. kt/vT chunk staged in LDS; P->A-frag via wave-private
// LDS (no barrier). Split-precision PV (hi+lo bf16).
#define KP 72  // LDS row pad: 144B, keeps 16B alignment for b128
__global__ __launch_bounds__(256, 4) void attn(
    const __hip_bfloat16* __restrict__ qb, const __hip_bfloat16* __restrict__ ktb,
    const __hip_bfloat16* __restrict__ vT, const int* __restrict__ mask,
    float* __restrict__ out) {
  __shared__ __hip_bfloat16 kts[64][KP];   // [key][dim]
  __shared__ __hip_bfloat16 vts[64][KP];   // [dim][key]
  __shared__ float pbuf[4][16][66];        // per-wave [q][key]
  const int q0 = blockIdx.x * 64, h = blockIdx.y, b = blockIdx.z;
  const int tid = threadIdx.x, wid = tid >> 6, lane = tid & 63;
  const int l15 = lane & 15, l4 = lane >> 4;
  const __hip_bfloat16* qh = qb + (size_t)b * S_ * D_ + h * HD_;
  const __hip_bfloat16* kh = ktb + (size_t)b * S_ * D_ + h * HD_;
  const __hip_bfloat16* vh = vT + (size_t)(b * H_ + h) * HD_ * S_;
  const int srow = tid >> 2;           // 0..63
  const int scol = (tid & 3) * 8;      // 0,8,16,24

  // q A-frags (row m=l15 = query, k = l4*8..+7 / +32)
  const int qrow = q0 + wid * 16 + l15;
  const short8 aq0 = *(const short8*)(qh + (size_t)qrow * D_ + l4 * 8);
  const short8 aq1 = *(const short8*)(qh + (size_t)qrow * D_ + 32 + l4 * 8);

  float mq[4];
  for (int r = 0; r < 4; ++r)
    mq[r] = (mask[b * S_ + q0 + wid * 16 + l4 * 4 + r] != 0) ? 0.125f : 0.f;

  float m_r[4] = {-1e30f, -1e30f, -1e30f, -1e30f};
  float l_r[4] = {0.f, 0.f, 0.f, 0.f};
  const float4v zz = {0.f, 0.f, 0.f, 0.f};
  float4v oacc[4] = {zz, zz, zz, zz};

  // prefetch chunk 0
  short8 gk0 = *(const short8*)(kh + (size_t)srow * D_ + scol);
  short8 gk1 = *(const short8*)(kh + (size_t)srow * D_ + scol + 32);
  short8 gv0 = *(const short8*)(vh + (size_t)srow * S_ + scol);
  short8 gv1 = *(const short8*)(vh + (size_t)srow * S_ + scol + 32);

  for (int c = 0; c < 32; ++c) {
    __syncthreads();  // prior chunk's frag reads done
    *(short8*)&kts[srow][scol] = gk0;
    *(short8*)&kts[srow][scol + 32] = gk1;
    *(short8*)&vts[srow][scol] = gv0;
    *(short8*)&vts[srow][scol + 32] = gv1;
    __syncthreads();  // staging visible
    if (c < 31) {     // prefetch next chunk during compute
      const int ck = (c + 1) * 64;
      gk0 = *(const short8*)(kh + (size_t)(ck + srow) * D_ + scol);
      gk1 = *(const short8*)(kh + (size_t)(ck + srow) * D_ + scol + 32);
      gv0 = *(const short8*)(vh + (size_t)srow * S_ + ck + scol);
      gv1 = *(const short8*)(vh + (size_t)srow * S_ + ck + scol + 32);
    }
    // ---- QK: 4 key-tiles of 16; C row = query l4*4+r, col = key l15 ----
    float4v x[4];
    for (int t = 0; t < 4; ++t) {
      const short8 b0 = *(const short8*)&kts[t * 16 + l15][l4 * 8];
      const short8 b1 = *(const short8*)&kts[t * 16 + l15][32 + l4 * 8];
      float4v cc = zz;
      cc = __builtin_amdgcn_mfma_f32_16x16x32_bf16(aq0, b0, cc, 0, 0, 0);
      cc = __builtin_amdgcn_mfma_f32_16x16x32_bf16(aq1, b1, cc, 0, 0, 0);
      x[t] = cc;
    }
    for (int t = 0; t < 4; ++t)
      for (int r = 0; r < 4; ++r) x[t][r] *= mq[r];  // scale or mask->0
    // ---- online softmax: per query row r, reduce over 16 l15-lanes ----
    float p[4][4], alpha[4], rs[4];
    for (int r = 0; r < 4; ++r) {
      float cm = fmaxf(fmaxf(x[0][r], x[1][r]), fmaxf(x[2][r], x[3][r]));
      for (int o = 1; o < 16; o <<= 1) cm = fmaxf(cm, __shfl_xor(cm, o));
      const float mn = fmaxf(m_r[r], cm);
      alpha[r] = __expf(m_r[r] - mn);
      m_r[r] = mn;
      float s = 0.f;
      for (int t = 0; t < 4; ++t) { p[t][r] = __expf(x[t][r] - mn); s += p[t][r]; }
      for (int o = 1; o < 16; o <<= 1) s += __shfl_xor(s, o);
      rs[r] = s;
    }
    for (int r = 0; r < 4; ++r) l_r[r] = l_r[r] * alpha[r] + rs[r];
    for (int nt = 0; nt < 4; ++nt)
      for (int r = 0; r < 4; ++r) oacc[nt][r] *= alpha[r];
    // ---- P -> A-frag via wave-private LDS (in-order DS pipe, no barrier) ----
    for (int t = 0; t < 4; ++t)
      for (int r = 0; r < 4; ++r)
        pbuf[wid][l4 * 4 + r][t * 16 + l15] = p[t][r];
    for (int k2 = 0; k2 < 2; ++k2) {
      const float* pr = &pbuf[wid][l15][k2 * 32 + l4 * 8];
      const float4v p0 = *(const float4v*)pr;
      const float4v p1 = *(const float4v*)(pr + 4);
      short8 hi, lo;
      for (int j = 0; j < 4; ++j) {
        hi[j] = f2bs(p0[j]);     lo[j] = f2bs(p0[j] - bs2f(hi[j]));
        hi[4 + j] = f2bs(p1[j]); lo[4 + j] = f2bs(p1[j] - bs2f(hi[4 + j]));
      }
      for (int nt = 0; nt < 4; ++nt) {
        const short8 bv = *(const short8*)&vts[nt * 16 + l15][k2 * 32 + l4 * 8];
        oacc[nt] = __builtin_amdgcn_mfma_f32_16x16x32_bf16(hi, bv, oacc[nt], 0, 0, 0);
        oacc[nt] = __builtin_amdgcn_mfma_f32_16x16x32_bf16(lo, bv, oacc[nt], 0, 0, 0);
      }
    }
  }
  // ---- epilogue: normalize, store fp32 ----
  float invl[4];
  for (int r = 0; r < 4; ++r) invl[r] = 1.f / l_r[r];
  for (int nt = 0; nt < 4; ++nt)
    for (int r = 0; r < 4; ++r) {
      const int row = q0 + wid * 16 + l4 * 4 + r;
      out[(size_t)(b * S_ + row) * D_ + h * HD_ + nt * 16 + l15] = oacc[nt][r] * invl[r];
    }
}

extern "C" void kernel_launch(void* const* d_in, const int* in_sizes, int n_in,
                              void* d_out, int out_size, void* d_ws, size_t ws_size,
                              hipStream_t stream) {
  const float* hs = (const float*)d_in[0];
  const int* mask = (const int*)d_in[1];
  const float* Wq = (const float*)d_in[2];
  const float* bq = (const float*)d_in[3];
  const float* Wk = (const float*)d_in[4];
  const float* bk = (const float*)d_in[5];
  float* out = (float*)d_out;
  char* ws = (char*)d_ws;
  const size_t MB = 1u << 20;
  __hip_bfloat16* q_b = (__hip_bfloat16*)(ws + 0 * MB);   // [B,S,D] bf16, 8MB
  __hip_bfloat16* k_b = (__hip_bfloat16*)(ws + 8 * MB);   // k then softplus(k), 8MB
  __hip_bfloat16* vT  = (__hip_bfloat16*)(ws + 16 * MB);  // [B,H,HD,S] 8MB
  __hip_bfloat16* Wqt = (__hip_bfloat16*)(ws + 24 * MB);  // 2MB
  __hip_bfloat16* Wkt = (__hip_bfloat16*)(ws + 26 * MB);  // 2MB

  transpose_w<<<dim3(16, 16, 2), 256, 0, stream>>>(Wq, Wk, Wqt, Wkt);
  gemm_qk<<<dim3(8, 32, 2), 256, 0, stream>>>(hs, Wqt, Wkt, bq, bk, q_b, k_b);
  prep<<<dim3(32, 16, 2), 256, 0, stream>>>(q_b, k_b, vT);
  attn<<<dim3(32, 16, 2), 256, 0, stream>>>(q_b, k_b, vT, mask, out);
}

// Round 6
// 233.192 us; speedup vs baseline: 2.0766x; 1.2934x over previous
//
#include <hip/hip_runtime.h>
#include <hip/hip_bf16.h>

#define B_ 2
#define S_ 2048
#define D_ 1024
#define H_ 16
#define HD_ 64

typedef __attribute__((ext_vector_type(8))) short short8;
typedef __attribute__((ext_vector_type(4))) float float4v;

static __device__ inline float b2f(__hip_bfloat16 h) { return __bfloat162float(h); }

static __device__ inline short f2bs(float x) {
  __hip_bfloat16 h = __float2bfloat16(x);
  union { __hip_bfloat16 h; short s; } u; u.h = h; return u.s;
}
static __device__ inline float bs2f(short s) {
  union { short s; __hip_bfloat16 h; } u; u.s = s; return __bfloat162float(u.h);
}

// ---------------- Stage A: W fp32 [k][n] -> Wt bf16 [n][k] ----------------
__global__ __launch_bounds__(256) void transpose_w(
    const float* __restrict__ Wq, const float* __restrict__ Wk,
    __hip_bfloat16* __restrict__ Wqt, __hip_bfloat16* __restrict__ Wkt) {
  const float* W = blockIdx.z ? Wk : Wq;
  __hip_bfloat16* Wt = blockIdx.z ? Wkt : Wqt;
  __shared__ float t[64][65];
  const int n0 = blockIdx.x * 64, k0 = blockIdx.y * 64;
  const int c = threadIdx.x & 63, r0 = threadIdx.x >> 6;
  for (int i = 0; i < 16; ++i) {
    const int r = i * 4 + r0;
    t[c][r] = W[(size_t)(k0 + r) * D_ + n0 + c];
  }
  __syncthreads();
  for (int i = 0; i < 16; ++i) {
    const int rr = i * 4 + r0;
    Wt[(size_t)(n0 + rr) * D_ + k0 + c] = __float2bfloat16(t[rr][c]);
  }
}

// ---------------- Stage B: fused-bias GEMM, z=0 -> q, z=1 -> k ----------------
__global__ __launch_bounds__(256) void gemm_qk(
    const float* __restrict__ A,
    const __hip_bfloat16* __restrict__ Wqt, const __hip_bfloat16* __restrict__ Wkt,
    const float* __restrict__ bq, const float* __restrict__ bk,
    __hip_bfloat16* __restrict__ outq, __hip_bfloat16* __restrict__ outk) {
  const __hip_bfloat16* Wt = blockIdx.z ? Wkt : Wqt;
  const float* bias = blockIdx.z ? bk : bq;
  __hip_bfloat16* out = blockIdx.z ? outk : outq;
  const int m0 = blockIdx.y * 128, n0 = blockIdx.x * 128;
  __shared__ __hip_bfloat16 As[128 * 32];
  __shared__ __hip_bfloat16 Bs[128 * 32];
  const int tid = threadIdx.x, wid = tid >> 6, lane = tid & 63;
  const int wm = (wid >> 1) * 64, wn = (wid & 1) * 64;
  const int l15 = lane & 15, l4 = lane >> 4;
  float4v zz = {0.f, 0.f, 0.f, 0.f};
  float4v acc[4][4];
  for (int i = 0; i < 4; ++i)
    for (int j = 0; j < 4; ++j) acc[i][j] = zz;
  const int lrow = wid * 32 + (lane >> 2);
  const int lk8 = (lane & 3) * 8;
  for (int kb = 0; kb < 32; ++kb) {
    const int kc = kb * 32 + lk8;
    const float* pa0 = A + (size_t)(m0 + lrow) * D_ + kc;
    const float* pa1 = A + (size_t)(m0 + lrow + 16) * D_ + kc;
    const float4v a0l = ((const float4v*)pa0)[0], a0h = ((const float4v*)pa0)[1];
    const float4v a1l = ((const float4v*)pa1)[0], a1h = ((const float4v*)pa1)[1];
    const short8 w0 = *(const short8*)(Wt + (size_t)(n0 + lrow) * D_ + kc);
    const short8 w1 = *(const short8*)(Wt + (size_t)(n0 + lrow + 16) * D_ + kc);
    short8 a0, a1;
    for (int j = 0; j < 4; ++j) {
      a0[j] = f2bs(a0l[j]); a0[4 + j] = f2bs(a0h[j]);
      a1[j] = f2bs(a1l[j]); a1[4 + j] = f2bs(a1h[j]);
    }
    __syncthreads();
    *(short8*)(As + wid * 1024 + 8 * lane) = a0;
    *(short8*)(As + wid * 1024 + 512 + 8 * lane) = a1;
    *(short8*)(Bs + wid * 1024 + 8 * lane) = w0;
    *(short8*)(Bs + wid * 1024 + 512 + 8 * lane) = w1;
    __syncthreads();
    short8 af[4], bf[4];
    const int fo = l4 * 8;
    for (int rt = 0; rt < 4; ++rt)
      af[rt] = *(const short8*)(As + (wm + rt * 16 + l15) * 32 + fo);
    for (int ct = 0; ct < 4; ++ct)
      bf[ct] = *(const short8*)(Bs + (wn + ct * 16 + l15) * 32 + fo);
    for (int rt = 0; rt < 4; ++rt)
      for (int ct = 0; ct < 4; ++ct)
        acc[rt][ct] = __builtin_amdgcn_mfma_f32_16x16x32_bf16(af[rt], bf[ct], acc[rt][ct], 0, 0, 0);
  }
  float bv[4];
  for (int ct = 0; ct < 4; ++ct) bv[ct] = bias[n0 + wn + ct * 16 + l15];
  for (int rt = 0; rt < 4; ++rt)
    for (int ct = 0; ct < 4; ++ct) {
      const int col = n0 + wn + ct * 16 + l15;
      for (int r = 0; r < 4; ++r) {
        const int row = m0 + wm + rt * 16 + l4 * 4 + r;
        out[(size_t)row * D_ + col] = __float2bfloat16(acc[rt][ct][r] + bv[ct]);
      }
    }
}

// ------- Stage C: k <- softplus(k) (in place); vT[b,h,d,s] = q + k -------
__global__ __launch_bounds__(256) void prep(
    const __hip_bfloat16* __restrict__ qb, __hip_bfloat16* __restrict__ kb,
    __hip_bfloat16* __restrict__ vT) {
  __shared__ float vt[64][65];
  const int s0 = blockIdx.x * 64, h = blockIdx.y, b = blockIdx.z;
  const int d = threadIdx.x & 63, r0 = threadIdx.x >> 6;
  for (int i = 0; i < 16; ++i) {
    const int sl = i * 4 + r0;
    const size_t idx = (size_t)(b * S_ + s0 + sl) * D_ + h * HD_ + d;
    const float qv = b2f(qb[idx]);
    const float kv = b2f(kb[idx]);
    const float sp = (kv > 15.f) ? kv : log1pf(__expf(kv));  // softplus(k)
    kb[idx] = __float2bfloat16(sp);
    vt[d][sl] = qv + kv;
  }
  __syncthreads();
  for (int i = 0; i < 16; ++i) {
    const int dd = i * 4 + r0;
    vT[(size_t)((b * H_ + h) * HD_ + dd) * S_ + s0 + d] = __float2bfloat16(vt[dd][d]);
  }
}

// ---------------- Stage D: flash attention, 2-way key split ----------------
// 512 thr = 8 waves. Waves 0-3 (hf=0): keys 0..1023; waves 4-7 (hf=1): keys
// 1024..2047. Wave wid handles queries [q0+(wid&3)*16, +16). No max-tracking
// (exp-sum accumulated raw; scores bounded, fp32-safe). mask*scale folded
// into q-fragment (exact: x0.125 or x0). Transposed QK (X^T = KT*Q^T) puts
// query on the l15 lane axis; P C-layout -> PV B-operand via ds_bpermute
// (no LDS score buffer). Split-precision PV (hi+lo bf16). Key-halves merged
// via LDS overlay at the end (plain add — no rescale needed).
#define KP 72  // row pad: 144 B, 16B-aligned rows
__global__ __launch_bounds__(512, 8) void attn(
    const __hip_bfloat16* __restrict__ qb, const __hip_bfloat16* __restrict__ ktb,
    const __hip_bfloat16* __restrict__ vT, const int* __restrict__ mask,
    float* __restrict__ out) {
  __shared__ __hip_bfloat16 smem[4 * 64 * KP];  // kts[2][64][KP] ++ vts[2][64][KP]
  __hip_bfloat16 (*kts)[64][KP] = (__hip_bfloat16 (*)[64][KP])smem;
  __hip_bfloat16 (*vts)[64][KP] = (__hip_bfloat16 (*)[64][KP])(smem + 2 * 64 * KP);
  const int q0 = blockIdx.x * 64, h = blockIdx.y, b = blockIdx.z;
  const int tid = threadIdx.x, wid = tid >> 6, lane = tid & 63;
  const int l15 = lane & 15, l4 = lane >> 4;
  const int hf = wid >> 2, qt = wid & 3;
  const __hip_bfloat16* qh = qb + (size_t)b * S_ * D_ + h * HD_;
  const __hip_bfloat16* kh = ktb + (size_t)b * S_ * D_ + h * HD_;
  const __hip_bfloat16* vh = vT + (size_t)(b * H_ + h) * HD_ * S_;
  // staging map (per half): 256 thr cover 64 rows x 64 cols in 2x short8
  const int srow = (tid & 255) >> 2;
  const int scol = (tid & 3) * 8;

  // q B-fragment (n = query = l15), mask*scale folded in (exact pow2)
  const int qrow = q0 + qt * 16 + l15;
  const float mq = (mask[b * S_ + qrow] != 0) ? 0.125f : 0.f;
  const short8 rq0 = *(const short8*)(qh + (size_t)qrow * D_ + l4 * 8);
  const short8 rq1 = *(const short8*)(qh + (size_t)qrow * D_ + 32 + l4 * 8);
  short8 bq0, bq1;
  for (int j = 0; j < 8; ++j) {
    bq0[j] = f2bs(bs2f(rq0[j]) * mq);
    bq1[j] = f2bs(bs2f(rq1[j]) * mq);
  }

  const float4v zz = {0.f, 0.f, 0.f, 0.f};
  float4v oacc[4] = {zz, zz, zz, zz};
  float lsum = 0.f;

  // prefetch chunk 0 of this half
  const int kb0 = hf * 1024;
  short8 gk0 = *(const short8*)(kh + (size_t)(kb0 + srow) * D_ + scol);
  short8 gk1 = *(const short8*)(kh + (size_t)(kb0 + srow) * D_ + scol + 32);
  short8 gv0 = *(const short8*)(vh + (size_t)srow * S_ + kb0 + scol);
  short8 gv1 = *(const short8*)(vh + (size_t)srow * S_ + kb0 + scol + 32);

  for (int c = 0; c < 16; ++c) {
    __syncthreads();  // prior chunk's frag reads done
    *(short8*)&kts[hf][srow][scol] = gk0;
    *(short8*)&kts[hf][srow][scol + 32] = gk1;
    *(short8*)&vts[hf][srow][scol] = gv0;
    *(short8*)&vts[hf][srow][scol + 32] = gv1;
    __syncthreads();  // staging visible
    if (c < 15) {
      const int kb = hf * 1024 + (c + 1) * 64;
      gk0 = *(const short8*)(kh + (size_t)(kb + srow) * D_ + scol);
      gk1 = *(const short8*)(kh + (size_t)(kb + srow) * D_ + scol + 32);
      gv0 = *(const short8*)(vh + (size_t)srow * S_ + kb + scol);
      gv1 = *(const short8*)(vh + (size_t)srow * S_ + kb + scol + 32);
    }
#pragma unroll
    for (int k2 = 0; k2 < 2; ++k2) {  // 32-key subchunk
      // --- QK^T for tiles t = 2*k2, 2*k2+1: D row = key-local, col = query ---
      float p[2][4];
#pragma unroll
      for (int th = 0; th < 2; ++th) {
        const int t = k2 * 2 + th;
        const short8 ak0 = *(const short8*)&kts[hf][t * 16 + l15][l4 * 8];
        const short8 ak1 = *(const short8*)&kts[hf][t * 16 + l15][32 + l4 * 8];
        float4v cc = zz;
        cc = __builtin_amdgcn_mfma_f32_16x16x32_bf16(ak0, bq0, cc, 0, 0, 0);
        cc = __builtin_amdgcn_mfma_f32_16x16x32_bf16(ak1, bq1, cc, 0, 0, 0);
#pragma unroll
        for (int r = 0; r < 4; ++r) {
          p[th][r] = __expf(cc[r]);
          lsum += p[th][r];
        }
      }
      // --- P^T -> PV B-frag: lane needs key = k2*32 + l4*8 + j, query = l15.
      // Source: tile th=(l4>>1), quad=(l4&1)*2+(j>>2), reg=j&3, same l15. ---
      short8 hi, lo;
#pragma unroll
      for (int j = 0; j < 8; ++j) {
        const int srcl = (((l4 & 1) * 2 + (j >> 2)) << 4) + l15;
        const float va = __shfl(p[0][j & 3], srcl);
        const float vb = __shfl(p[1][j & 3], srcl);
        const float pv = (l4 & 2) ? vb : va;
        hi[j] = f2bs(pv);
        lo[j] = f2bs(pv - bs2f(hi[j]));
      }
      // --- PV: O^T[d][q] += VT[d][key] * P^T[key][q] ---
#pragma unroll
      for (int dt = 0; dt < 4; ++dt) {
        const short8 av = *(const short8*)&vts[hf][dt * 16 + l15][k2 * 32 + l4 * 8];
        oacc[dt] = __builtin_amdgcn_mfma_f32_16x16x32_bf16(av, hi, oacc[dt], 0, 0, 0);
        oacc[dt] = __builtin_amdgcn_mfma_f32_16x16x32_bf16(av, lo, oacc[dt], 0, 0, 0);
      }
    }
  }
  // ---- epilogue: reduce l over quads (query = l15 in every quad) ----
  const float l16 = lsum + __shfl_xor(lsum, 16);
  const float lq = l16 + __shfl_xor(l16, 32);
  __syncthreads();  // all frag reads done -> overlay merge buffer on smem
  float* mbuf = (float*)smem;              // [4][16][68]
  float* mlb = (float*)smem + 4 * 16 * 68; // [4][16]
  if (hf == 1) {
#pragma unroll
    for (int dt = 0; dt < 4; ++dt)
#pragma unroll
      for (int r = 0; r < 4; ++r)
        mbuf[(qt * 16 + l15) * 68 + dt * 16 + l4 * 4 + r] = oacc[dt][r];
    if (l4 == 0) mlb[qt * 16 + l15] = lq;
  }
  __syncthreads();
  if (hf == 0) {
    const float linv = 1.f / (lq + mlb[qt * 16 + l15]);
#pragma unroll
    for (int dt = 0; dt < 4; ++dt) {
      const float4v part = *(const float4v*)&mbuf[(qt * 16 + l15) * 68 + dt * 16 + l4 * 4];
      float4v v;
#pragma unroll
      for (int r = 0; r < 4; ++r) v[r] = (oacc[dt][r] + part[r]) * linv;
      *(float4v*)(out + (size_t)(b * S_ + qrow) * D_ + h * HD_ + dt * 16 + l4 * 4) = v;
    }
  }
}

extern "C" void kernel_launch(void* const* d_in, const int* in_sizes, int n_in,
                              void* d_out, int out_size, void* d_ws, size_t ws_size,
                              hipStream_t stream) {
  const float* hs = (const float*)d_in[0];
  const int* mask = (const int*)d_in[1];
  const float* Wq = (const float*)d_in[2];
  const float* bq = (const float*)d_in[3];
  const float* Wk = (const float*)d_in[4];
  const float* bk = (const float*)d_in[5];
  float* out = (float*)d_out;
  char* ws = (char*)d_ws;
  const size_t MB = 1u << 20;
  __hip_bfloat16* q_b = (__hip_bfloat16*)(ws + 0 * MB);   // [B,S,D] bf16, 8MB
  __hip_bfloat16* k_b = (__hip_bfloat16*)(ws + 8 * MB);   // k then softplus(k), 8MB
  __hip_bfloat16* vT  = (__hip_bfloat16*)(ws + 16 * MB);  // [B,H,HD,S] 8MB
  __hip_bfloat16* Wqt = (__hip_bfloat16*)(ws + 24 * MB);  // 2MB
  __hip_bfloat16* Wkt = (__hip_bfloat16*)(ws + 26 * MB);  // 2MB

  transpose_w<<<dim3(16, 16, 2), 256, 0, stream>>>(Wq, Wk, Wqt, Wkt);
  gemm_qk<<<dim3(8, 32, 2), 256, 0, stream>>>(hs, Wqt, Wkt, bq, bk, q_b, k_b);
  prep<<<dim3(32, 16, 2), 256, 0, stream>>>(q_b, k_b, vT);
  attn<<<dim3(32, 16, 2), 512, 0, stream>>>(q_b, k_b, vT, mask, out);
}

// Round 7
// 205.394 us; speedup vs baseline: 2.3577x; 1.1353x over previous
//
#include <hip/hip_runtime.h>
#include <hip/hip_bf16.h>

#define B_ 2
#define S_ 2048
#define D_ 1024
#define H_ 16
#define HD_ 64

typedef __attribute__((ext_vector_type(8))) short short8;
typedef __attribute__((ext_vector_type(4))) float float4v;

static __device__ inline float b2f(__hip_bfloat16 h) { return __bfloat162float(h); }

static __device__ inline short f2bs(float x) {
  __hip_bfloat16 h = __float2bfloat16(x);
  union { __hip_bfloat16 h; short s; } u; u.h = h; return u.s;
}
static __device__ inline float bs2f(short s) {
  union { short s; __hip_bfloat16 h; } u; u.s = s; return __bfloat162float(u.h);
}

// ---------------- Stage A0: hs fp32 -> bf16 ----------------
__global__ __launch_bounds__(256) void cvt_hs(
    const float* __restrict__ in, __hip_bfloat16* __restrict__ out) {
  const size_t i = ((size_t)blockIdx.x * 256 + threadIdx.x) * 8;
  const float4v v0 = *(const float4v*)(in + i);
  const float4v v1 = *(const float4v*)(in + i + 4);
  short8 s;
  for (int j = 0; j < 4; ++j) { s[j] = f2bs(v0[j]); s[4 + j] = f2bs(v1[j]); }
  *(short8*)(out + i) = s;
}

// ---------------- Stage A: W fp32 [k][n] -> Wt bf16 [n][k] ----------------
__global__ __launch_bounds__(256) void transpose_w(
    const float* __restrict__ Wq, const float* __restrict__ Wk,
    __hip_bfloat16* __restrict__ Wqt, __hip_bfloat16* __restrict__ Wkt) {
  const float* W = blockIdx.z ? Wk : Wq;
  __hip_bfloat16* Wt = blockIdx.z ? Wkt : Wqt;
  __shared__ float t[64][65];
  const int n0 = blockIdx.x * 64, k0 = blockIdx.y * 64;
  const int c = threadIdx.x & 63, r0 = threadIdx.x >> 6;
  for (int i = 0; i < 16; ++i) {
    const int r = i * 4 + r0;
    t[c][r] = W[(size_t)(k0 + r) * D_ + n0 + c];
  }
  __syncthreads();
  for (int i = 0; i < 16; ++i) {
    const int rr = i * 4 + r0;
    Wt[(size_t)(n0 + rr) * D_ + k0 + c] = __float2bfloat16(t[rr][c]);
  }
}

// ---------------- Stage B: fused-bias GEMM (all-bf16), z=0 -> q, z=1 -> k ----
__global__ __launch_bounds__(256) void gemm_qk(
    const __hip_bfloat16* __restrict__ A,
    const __hip_bfloat16* __restrict__ Wqt, const __hip_bfloat16* __restrict__ Wkt,
    const float* __restrict__ bq, const float* __restrict__ bk,
    __hip_bfloat16* __restrict__ outq, __hip_bfloat16* __restrict__ outk) {
  const __hip_bfloat16* Wt = blockIdx.z ? Wkt : Wqt;
  const float* bias = blockIdx.z ? bk : bq;
  __hip_bfloat16* out = blockIdx.z ? outk : outq;
  const int m0 = blockIdx.y * 128, n0 = blockIdx.x * 128;
  __shared__ __hip_bfloat16 As[128 * 32];
  __shared__ __hip_bfloat16 Bs[128 * 32];
  const int tid = threadIdx.x, wid = tid >> 6, lane = tid & 63;
  const int wm = (wid >> 1) * 64, wn = (wid & 1) * 64;
  const int l15 = lane & 15, l4 = lane >> 4;
  float4v zz = {0.f, 0.f, 0.f, 0.f};
  float4v acc[4][4];
  for (int i = 0; i < 4; ++i)
    for (int j = 0; j < 4; ++j) acc[i][j] = zz;
  const int lrow = wid * 32 + (lane >> 2);
  const int lk8 = (lane & 3) * 8;
  for (int kb = 0; kb < 32; ++kb) {
    const int kc = kb * 32 + lk8;
    const short8 a0 = *(const short8*)(A + (size_t)(m0 + lrow) * D_ + kc);
    const short8 a1 = *(const short8*)(A + (size_t)(m0 + lrow + 16) * D_ + kc);
    const short8 w0 = *(const short8*)(Wt + (size_t)(n0 + lrow) * D_ + kc);
    const short8 w1 = *(const short8*)(Wt + (size_t)(n0 + lrow + 16) * D_ + kc);
    __syncthreads();
    *(short8*)(As + wid * 1024 + 8 * lane) = a0;
    *(short8*)(As + wid * 1024 + 512 + 8 * lane) = a1;
    *(short8*)(Bs + wid * 1024 + 8 * lane) = w0;
    *(short8*)(Bs + wid * 1024 + 512 + 8 * lane) = w1;
    __syncthreads();
    short8 af[4], bf[4];
    const int fo = l4 * 8;
    for (int rt = 0; rt < 4; ++rt)
      af[rt] = *(const short8*)(As + (wm + rt * 16 + l15) * 32 + fo);
    for (int ct = 0; ct < 4; ++ct)
      bf[ct] = *(const short8*)(Bs + (wn + ct * 16 + l15) * 32 + fo);
    for (int rt = 0; rt < 4; ++rt)
      for (int ct = 0; ct < 4; ++ct)
        acc[rt][ct] = __builtin_amdgcn_mfma_f32_16x16x32_bf16(af[rt], bf[ct], acc[rt][ct], 0, 0, 0);
  }
  float bv[4];
  for (int ct = 0; ct < 4; ++ct) bv[ct] = bias[n0 + wn + ct * 16 + l15];
  for (int rt = 0; rt < 4; ++rt)
    for (int ct = 0; ct < 4; ++ct) {
      const int col = n0 + wn + ct * 16 + l15;
      for (int r = 0; r < 4; ++r) {
        const int row = m0 + wm + rt * 16 + l4 * 4 + r;
        out[(size_t)row * D_ + col] = __float2bfloat16(acc[rt][ct][r] + bv[ct]);
      }
    }
}

// ------- Stage C: k <- softplus(k) (in place); vT[b,h,d,s] = q + k -------
__global__ __launch_bounds__(256) void prep(
    const __hip_bfloat16* __restrict__ qb, __hip_bfloat16* __restrict__ kb,
    __hip_bfloat16* __restrict__ vT) {
  __shared__ float vt[64][65];
  const int s0 = blockIdx.x * 64, h = blockIdx.y, b = blockIdx.z;
  const int d = threadIdx.x & 63, r0 = threadIdx.x >> 6;
  for (int i = 0; i < 16; ++i) {
    const int sl = i * 4 + r0;
    const size_t idx = (size_t)(b * S_ + s0 + sl) * D_ + h * HD_ + d;
    const float qv = b2f(qb[idx]);
    const float kv = b2f(kb[idx]);
    const float sp = (kv > 15.f) ? kv : log1pf(__expf(kv));  // softplus(k)
    kb[idx] = __float2bfloat16(sp);
    vt[d][sl] = qv + kv;
  }
  __syncthreads();
  for (int i = 0; i < 16; ++i) {
    const int dd = i * 4 + r0;
    vT[(size_t)((b * H_ + h) * HD_ + dd) * S_ + s0 + d] = __float2bfloat16(vt[dd][d]);
  }
}

// ---------------- Stage D: flash attention, 2-way key split, 128 q/block ----
// 512 thr = 8 waves; hf=wid>>2 picks key half, qt=wid&3 picks a 32-query
// stripe (two 16-query MFMA tiles A/B). No max-tracking; mask*scale folded
// into q-frags; transposed QK; P-transform via shuffles; bf16 P (no lo term).
#define KP 72  // row pad: 144 B, 16B-aligned rows
__global__ __launch_bounds__(512, 4) void attn(
    const __hip_bfloat16* __restrict__ qb, const __hip_bfloat16* __restrict__ ktb,
    const __hip_bfloat16* __restrict__ vT, const int* __restrict__ mask,
    float* __restrict__ out) {
  __shared__ __hip_bfloat16 smem[4 * 64 * KP];  // kts[2][64][KP] ++ vts[2][64][KP]
  __hip_bfloat16 (*kts)[64][KP] = (__hip_bfloat16 (*)[64][KP])smem;
  __hip_bfloat16 (*vts)[64][KP] = (__hip_bfloat16 (*)[64][KP])(smem + 2 * 64 * KP);
  const int q0 = blockIdx.x * 128, h = blockIdx.y, b = blockIdx.z;
  const int tid = threadIdx.x, wid = tid >> 6, lane = tid & 63;
  const int l15 = lane & 15, l4 = lane >> 4;
  const int hf = wid >> 2, qt = wid & 3;
  const __hip_bfloat16* qh = qb + (size_t)b * S_ * D_ + h * HD_;
  const __hip_bfloat16* kh = ktb + (size_t)b * S_ * D_ + h * HD_;
  const __hip_bfloat16* vh = vT + (size_t)(b * H_ + h) * HD_ * S_;
  const int srow = (tid & 255) >> 2;
  const int scol = (tid & 3) * 8;

  // two q B-fragments (n = query = l15), mask*scale folded in (exact pow2)
  const int qlA = qt * 32 + l15, qlB = qlA + 16;   // query-local in block
  const int qrA = q0 + qlA, qrB = q0 + qlB;        // global query rows
  const float mqA = (mask[b * S_ + qrA] != 0) ? 0.125f : 0.f;
  const float mqB = (mask[b * S_ + qrB] != 0) ? 0.125f : 0.f;
  const short8 rA0 = *(const short8*)(qh + (size_t)qrA * D_ + l4 * 8);
  const short8 rA1 = *(const short8*)(qh + (size_t)qrA * D_ + 32 + l4 * 8);
  const short8 rB0 = *(const short8*)(qh + (size_t)qrB * D_ + l4 * 8);
  const short8 rB1 = *(const short8*)(qh + (size_t)qrB * D_ + 32 + l4 * 8);
  short8 bqA0, bqA1, bqB0, bqB1;
  for (int j = 0; j < 8; ++j) {
    bqA0[j] = f2bs(bs2f(rA0[j]) * mqA);
    bqA1[j] = f2bs(bs2f(rA1[j]) * mqA);
    bqB0[j] = f2bs(bs2f(rB0[j]) * mqB);
    bqB1[j] = f2bs(bs2f(rB1[j]) * mqB);
  }

  const float4v zz = {0.f, 0.f, 0.f, 0.f};
  float4v oaccA[4] = {zz, zz, zz, zz};
  float4v oaccB[4] = {zz, zz, zz, zz};
  float lsumA = 0.f, lsumB = 0.f;

  // prefetch chunk 0 of this half
  const int kb0 = hf * 1024;
  short8 gk0 = *(const short8*)(kh + (size_t)(kb0 + srow) * D_ + scol);
  short8 gk1 = *(const short8*)(kh + (size_t)(kb0 + srow) * D_ + scol + 32);
  short8 gv0 = *(const short8*)(vh + (size_t)srow * S_ + kb0 + scol);
  short8 gv1 = *(const short8*)(vh + (size_t)srow * S_ + kb0 + scol + 32);

  for (int c = 0; c < 16; ++c) {
    __syncthreads();
    *(short8*)&kts[hf][srow][scol] = gk0;
    *(short8*)&kts[hf][srow][scol + 32] = gk1;
    *(short8*)&vts[hf][srow][scol] = gv0;
    *(short8*)&vts[hf][srow][scol + 32] = gv1;
    __syncthreads();
    if (c < 15) {
      const int kb = hf * 1024 + (c + 1) * 64;
      gk0 = *(const short8*)(kh + (size_t)(kb + srow) * D_ + scol);
      gk1 = *(const short8*)(kh + (size_t)(kb + srow) * D_ + scol + 32);
      gv0 = *(const short8*)(vh + (size_t)srow * S_ + kb + scol);
      gv1 = *(const short8*)(vh + (size_t)srow * S_ + kb + scol + 32);
    }
#pragma unroll
    for (int k2 = 0; k2 < 2; ++k2) {  // 32-key subchunk
      float pA[2][4], pB[2][4];
#pragma unroll
      for (int th = 0; th < 2; ++th) {
        const int t = k2 * 2 + th;
        const short8 ak0 = *(const short8*)&kts[hf][t * 16 + l15][l4 * 8];
        const short8 ak1 = *(const short8*)&kts[hf][t * 16 + l15][32 + l4 * 8];
        float4v cA = zz, cB = zz;
        cA = __builtin_amdgcn_mfma_f32_16x16x32_bf16(ak0, bqA0, cA, 0, 0, 0);
        cA = __builtin_amdgcn_mfma_f32_16x16x32_bf16(ak1, bqA1, cA, 0, 0, 0);
        cB = __builtin_amdgcn_mfma_f32_16x16x32_bf16(ak0, bqB0, cB, 0, 0, 0);
        cB = __builtin_amdgcn_mfma_f32_16x16x32_bf16(ak1, bqB1, cB, 0, 0, 0);
#pragma unroll
        for (int r = 0; r < 4; ++r) {
          pA[th][r] = __expf(cA[r]); lsumA += pA[th][r];
          pB[th][r] = __expf(cB[r]); lsumB += pB[th][r];
        }
      }
      // P^T (C-layout) -> PV B-frag: key = k2*32 + l4*8 + j, query = l15.
      short8 hiA, hiB;
#pragma unroll
      for (int j = 0; j < 8; ++j) {
        const int srcl = (((l4 & 1) * 2 + (j >> 2)) << 4) + l15;
        const float vaA = __shfl(pA[0][j & 3], srcl);
        const float vbA = __shfl(pA[1][j & 3], srcl);
        hiA[j] = f2bs((l4 & 2) ? vbA : vaA);
        const float vaB = __shfl(pB[0][j & 3], srcl);
        const float vbB = __shfl(pB[1][j & 3], srcl);
        hiB[j] = f2bs((l4 & 2) ? vbB : vaB);
      }
#pragma unroll
      for (int dt = 0; dt < 4; ++dt) {
        const short8 av = *(const short8*)&vts[hf][dt * 16 + l15][k2 * 32 + l4 * 8];
        oaccA[dt] = __builtin_amdgcn_mfma_f32_16x16x32_bf16(av, hiA, oaccA[dt], 0, 0, 0);
        oaccB[dt] = __builtin_amdgcn_mfma_f32_16x16x32_bf16(av, hiB, oaccB[dt], 0, 0, 0);
      }
    }
  }
  // ---- epilogue: reduce l over quads, merge key-halves via LDS overlay ----
  float lA = lsumA + __shfl_xor(lsumA, 16); lA += __shfl_xor(lA, 32);
  float lB = lsumB + __shfl_xor(lsumB, 16); lB += __shfl_xor(lB, 32);
  __syncthreads();
  float* mbuf = (float*)smem;                 // [128][68]
  float* mlb = (float*)smem + 128 * 68;       // [128]
  if (hf == 1) {
#pragma unroll
    for (int dt = 0; dt < 4; ++dt)
#pragma unroll
      for (int r = 0; r < 4; ++r) {
        mbuf[qlA * 68 + dt * 16 + l4 * 4 + r] = oaccA[dt][r];
        mbuf[qlB * 68 + dt * 16 + l4 * 4 + r] = oaccB[dt][r];
      }
    if (l4 == 0) { mlb[qlA] = lA; mlb[qlB] = lB; }
  }
  __syncthreads();
  if (hf == 0) {
    const float liA = 1.f / (lA + mlb[qlA]);
    const float liB = 1.f / (lB + mlb[qlB]);
#pragma unroll
    for (int dt = 0; dt < 4; ++dt) {
      const float4v pa = *(const float4v*)&mbuf[qlA * 68 + dt * 16 + l4 * 4];
      const float4v pb = *(const float4v*)&mbuf[qlB * 68 + dt * 16 + l4 * 4];
      float4v va, vb;
#pragma unroll
      for (int r = 0; r < 4; ++r) {
        va[r] = (oaccA[dt][r] + pa[r]) * liA;
        vb[r] = (oaccB[dt][r] + pb[r]) * liB;
      }
      *(float4v*)(out + (size_t)(b * S_ + qrA) * D_ + h * HD_ + dt * 16 + l4 * 4) = va;
      *(float4v*)(out + (size_t)(b * S_ + qrB) * D_ + h * HD_ + dt * 16 + l4 * 4) = vb;
    }
  }
}

extern "C" void kernel_launch(void* const* d_in, const int* in_sizes, int n_in,
                              void* d_out, int out_size, void* d_ws, size_t ws_size,
                              hipStream_t stream) {
  const float* hs = (const float*)d_in[0];
  const int* mask = (const int*)d_in[1];
  const float* Wq = (const float*)d_in[2];
  const float* bq = (const float*)d_in[3];
  const float* Wk = (const float*)d_in[4];
  const float* bk = (const float*)d_in[5];
  float* out = (float*)d_out;
  char* ws = (char*)d_ws;
  const size_t MB = 1u << 20;
  __hip_bfloat16* q_b = (__hip_bfloat16*)(ws + 0 * MB);   // [B,S,D] bf16, 8MB
  __hip_bfloat16* k_b = (__hip_bfloat16*)(ws + 8 * MB);   // k then softplus(k), 8MB
  __hip_bfloat16* hsb = (__hip_bfloat16*)(ws + 16 * MB);  // hs bf16; later reused as vT
  __hip_bfloat16* vT  = (__hip_bfloat16*)(ws + 16 * MB);  // [B,H,HD,S] 8MB (aliases hsb)
  __hip_bfloat16* Wqt = (__hip_bfloat16*)(ws + 24 * MB);  // 2MB
  __hip_bfloat16* Wkt = (__hip_bfloat16*)(ws + 26 * MB);  // 2MB

  cvt_hs<<<dim3(2048), 256, 0, stream>>>(hs, hsb);
  transpose_w<<<dim3(16, 16, 2), 256, 0, stream>>>(Wq, Wk, Wqt, Wkt);
  gemm_qk<<<dim3(8, 32, 2), 256, 0, stream>>>(hsb, Wqt, Wkt, bq, bk, q_b, k_b);
  prep<<<dim3(32, 16, 2), 256, 0, stream>>>(q_b, k_b, vT);  // overwrites hsb (done with it)
  attn<<<dim3(16, 16, 2), 512, 0, stream>>>(q_b, k_b, vT, mask, out);
}

// Round 9
// 195.111 us; speedup vs baseline: 2.4819x; 1.0527x over previous
//
#include <hip/hip_runtime.h>
#include <hip/hip_bf16.h>

#define B_ 2
#define S_ 2048
#define D_ 1024
#define H_ 16
#define HD_ 64

typedef __attribute__((ext_vector_type(8))) short short8;
typedef __attribute__((ext_vector_type(4))) short short4v;
typedef __attribute__((ext_vector_type(4))) float float4v;

typedef const __attribute__((address_space(1))) void* gas_ptr;
typedef __attribute__((address_space(3))) void* las_ptr;

static __device__ inline void gl_lds16(const void* g, void* l) {
  // async global->LDS, 16B/lane, LDS dest = wave-uniform base + lane*16
  __builtin_amdgcn_global_load_lds((gas_ptr)g, (las_ptr)l, 16, 0, 0);
}

static __device__ inline float b2f(__hip_bfloat16 h) { return __bfloat162float(h); }

static __device__ inline short f2bs(float x) {
  __hip_bfloat16 h = __float2bfloat16(x);
  union { __hip_bfloat16 h; short s; } u; u.h = h; return u.s;
}
static __device__ inline float bs2f(short s) {
  union { short s; __hip_bfloat16 h; } u; u.s = s; return __bfloat162float(u.h);
}

static __device__ inline float4v mfma32(short8 a, short8 b, float4v c) {
  return __builtin_amdgcn_mfma_f32_16x16x32_bf16(a, b, c, 0, 0, 0);
}
// v_mfma_f32_16x16x16_bf16 (4xbf16 A/B operands) — gfx90a-era "_1k" builtin,
// instruction present on gfx950 (cdna4_isa.md §10).
static __device__ inline float4v mfma16(short4v a, short4v b, float4v c) {
  return __builtin_amdgcn_mfma_f32_16x16x16bf16_1k(a, b, c, 0, 0, 0);
}

// ------- Stage A (fused): z<2 -> W transpose fp32->bf16; z==2 -> hs cvt -------
__global__ __launch_bounds__(256) void pre(
    const float* __restrict__ Wq, const float* __restrict__ Wk,
    const float* __restrict__ hs,
    __hip_bfloat16* __restrict__ Wqt, __hip_bfloat16* __restrict__ Wkt,
    __hip_bfloat16* __restrict__ hsb) {
  if (blockIdx.z == 2) {
    const int blk = blockIdx.y * 16 + blockIdx.x;
    for (int it = 0; it < 8; ++it) {
      const size_t i = (size_t)blk * 16384 + it * 2048 + threadIdx.x * 8;
      const float4v v0 = *(const float4v*)(hs + i);
      const float4v v1 = *(const float4v*)(hs + i + 4);
      short8 s;
      for (int j = 0; j < 4; ++j) { s[j] = f2bs(v0[j]); s[4 + j] = f2bs(v1[j]); }
      *(short8*)(hsb + i) = s;
    }
    return;
  }
  const float* W = blockIdx.z ? Wk : Wq;
  __hip_bfloat16* Wt = blockIdx.z ? Wkt : Wqt;
  __shared__ float t[64][65];
  const int n0 = blockIdx.x * 64, k0 = blockIdx.y * 64;
  const int c = threadIdx.x & 63, r0 = threadIdx.x >> 6;
  for (int i = 0; i < 16; ++i) {
    const int r = i * 4 + r0;
    t[c][r] = W[(size_t)(k0 + r) * D_ + n0 + c];
  }
  __syncthreads();
  for (int i = 0; i < 16; ++i) {
    const int rr = i * 4 + r0;
    Wt[(size_t)(n0 + rr) * D_ + k0 + c] = __float2bfloat16(t[rr][c]);
  }
}

// ---- Stage B: fused-bias GEMM (bf16), global_load_lds + LDS double buffer ----
__global__ __launch_bounds__(256) void gemm_qk(
    const __hip_bfloat16* __restrict__ A,
    const __hip_bfloat16* __restrict__ Wqt, const __hip_bfloat16* __restrict__ Wkt,
    const float* __restrict__ bq, const float* __restrict__ bk,
    __hip_bfloat16* __restrict__ outq, __hip_bfloat16* __restrict__ outk) {
  const __hip_bfloat16* Wt = blockIdx.z ? Wkt : Wqt;
  const float* bias = blockIdx.z ? bk : bq;
  __hip_bfloat16* out = blockIdx.z ? outk : outq;
  const int m0 = blockIdx.y * 128, n0 = blockIdx.x * 128;
  __shared__ __hip_bfloat16 As[2][128 * 32];
  __shared__ __hip_bfloat16 Bs[2][128 * 32];
  const int tid = threadIdx.x, wid = tid >> 6, lane = tid & 63;
  const int wm = (wid >> 1) * 64, wn = (wid & 1) * 64;
  const int l15 = lane & 15, l4 = lane >> 4;
  float4v zz = {0.f, 0.f, 0.f, 0.f};
  float4v acc[4][4];
  for (int i = 0; i < 4; ++i)
    for (int j = 0; j < 4; ++j) acc[i][j] = zz;
  // staging map: LDS elem off wid*1024 + c*512 + 8*lane <-> row=wid*32+c*16+lane/4, k8=(lane&3)*8
  const int lrow = wid * 32 + (lane >> 2);
  const int lk8 = (lane & 3) * 8;
  // preload chunk 0 into buffer 0
  gl_lds16(A + (size_t)(m0 + lrow) * D_ + lk8, As[0] + wid * 1024);
  gl_lds16(A + (size_t)(m0 + lrow + 16) * D_ + lk8, As[0] + wid * 1024 + 512);
  gl_lds16(Wt + (size_t)(n0 + lrow) * D_ + lk8, Bs[0] + wid * 1024);
  gl_lds16(Wt + (size_t)(n0 + lrow + 16) * D_ + lk8, Bs[0] + wid * 1024 + 512);
  int p = 0;
  for (int kb = 0; kb < 32; ++kb) {
    __syncthreads();  // drains vmcnt: buf[p] staged; prev iter's frag reads done
    if (kb < 31) {    // async loads into buf[p^1], in flight across compute
      const int kc = (kb + 1) * 32 + lk8;
      gl_lds16(A + (size_t)(m0 + lrow) * D_ + kc, As[p ^ 1] + wid * 1024);
      gl_lds16(A + (size_t)(m0 + lrow + 16) * D_ + kc, As[p ^ 1] + wid * 1024 + 512);
      gl_lds16(Wt + (size_t)(n0 + lrow) * D_ + kc, Bs[p ^ 1] + wid * 1024);
      gl_lds16(Wt + (size_t)(n0 + lrow + 16) * D_ + kc, Bs[p ^ 1] + wid * 1024 + 512);
    }
    short8 af[4], bf[4];
    const int fo = l4 * 8;
    for (int rt = 0; rt < 4; ++rt)
      af[rt] = *(const short8*)(As[p] + (wm + rt * 16 + l15) * 32 + fo);
    for (int ct = 0; ct < 4; ++ct)
      bf[ct] = *(const short8*)(Bs[p] + (wn + ct * 16 + l15) * 32 + fo);
    for (int rt = 0; rt < 4; ++rt)
      for (int ct = 0; ct < 4; ++ct)
        acc[rt][ct] = mfma32(af[rt], bf[ct], acc[rt][ct]);
    p ^= 1;
  }
  float bv[4];
  for (int ct = 0; ct < 4; ++ct) bv[ct] = bias[n0 + wn + ct * 16 + l15];
  for (int rt = 0; rt < 4; ++rt)
    for (int ct = 0; ct < 4; ++ct) {
      const int col = n0 + wn + ct * 16 + l15;
      for (int r = 0; r < 4; ++r) {
        const int row = m0 + wm + rt * 16 + l4 * 4 + r;
        out[(size_t)row * D_ + col] = __float2bfloat16(acc[rt][ct][r] + bv[ct]);
      }
    }
}

// ------- Stage C: k <- softplus(k) (in place); vT[b,h,d,s] = q + k -------
__global__ __launch_bounds__(256) void prep(
    const __hip_bfloat16* __restrict__ qb, __hip_bfloat16* __restrict__ kb,
    __hip_bfloat16* __restrict__ vT) {
  __shared__ float vt[64][65];
  const int s0 = blockIdx.x * 64, h = blockIdx.y, b = blockIdx.z;
  const int d = threadIdx.x & 63, r0 = threadIdx.x >> 6;
  for (int i = 0; i < 16; ++i) {
    const int sl = i * 4 + r0;
    const size_t idx = (size_t)(b * S_ + s0 + sl) * D_ + h * HD_ + d;
    const float qv = b2f(qb[idx]);
    const float kv = b2f(kb[idx]);
    const float sp = (kv > 15.f) ? kv : log1pf(__expf(kv));  // softplus(k)
    kb[idx] = __float2bfloat16(sp);
    vt[d][sl] = qv + kv;
  }
  __syncthreads();
  for (int i = 0; i < 16; ++i) {
    const int dd = i * 4 + r0;
    vT[(size_t)((b * H_ + h) * HD_ + dd) * S_ + s0 + d] = __float2bfloat16(vt[dd][d]);
  }
}

// ------- Stage D: flash attention, 2-way key split, 128 q/block, dbuf -------
// 512 thr = 8 waves; hf=wid>>2 key half, qt=wid&3 -> 32-query stripe (tiles
// A/B). No max-tracking; mask*scale folded into q-frags. QK^T (K=32) gives P
// in C-layout = B-operand layout of 16x16x16 MFMA -> PV needs NO transform.
// Single barrier per chunk (LDS double buffer).
#define KP 72  // row pad: 144 B, 16B-aligned rows
__global__ __launch_bounds__(512, 4) void attn(
    const __hip_bfloat16* __restrict__ qb, const __hip_bfloat16* __restrict__ ktb,
    const __hip_bfloat16* __restrict__ vT, const int* __restrict__ mask,
    float* __restrict__ out) {
  __shared__ __hip_bfloat16 smem[2][4 * 64 * KP];  // [buf][ kts[2][64][KP] ++ vts[2][64][KP] ]
  const int q0 = blockIdx.x * 128, h = blockIdx.y, b = blockIdx.z;
  const int tid = threadIdx.x, wid = tid >> 6, lane = tid & 63;
  const int l15 = lane & 15, l4 = lane >> 4;
  const int hf = wid >> 2, qt = wid & 3;
  const __hip_bfloat16* qh = qb + (size_t)b * S_ * D_ + h * HD_;
  const __hip_bfloat16* kh = ktb + (size_t)b * S_ * D_ + h * HD_;
  const __hip_bfloat16* vh = vT + (size_t)(b * H_ + h) * HD_ * S_;
  const int srow = (tid & 255) >> 2;
  const int scol = (tid & 3) * 8;
  const int koff = hf * 64 * KP;            // kts base (elements) within buffer
  const int voff = (2 + hf) * 64 * KP;      // vts base

  // two q B-fragments (n = query = l15), mask*scale folded in (exact pow2)
  const int qlA = qt * 32 + l15, qlB = qlA + 16;
  const int qrA = q0 + qlA, qrB = q0 + qlB;
  const float mqA = (mask[b * S_ + qrA] != 0) ? 0.125f : 0.f;
  const float mqB = (mask[b * S_ + qrB] != 0) ? 0.125f : 0.f;
  const short8 rA0 = *(const short8*)(qh + (size_t)qrA * D_ + l4 * 8);
  const short8 rA1 = *(const short8*)(qh + (size_t)qrA * D_ + 32 + l4 * 8);
  const short8 rB0 = *(const short8*)(qh + (size_t)qrB * D_ + l4 * 8);
  const short8 rB1 = *(const short8*)(qh + (size_t)qrB * D_ + 32 + l4 * 8);
  short8 bqA0, bqA1, bqB0, bqB1;
  for (int j = 0; j < 8; ++j) {
    bqA0[j] = f2bs(bs2f(rA0[j]) * mqA);
    bqA1[j] = f2bs(bs2f(rA1[j]) * mqA);
    bqB0[j] = f2bs(bs2f(rB0[j]) * mqB);
    bqB1[j] = f2bs(bs2f(rB1[j]) * mqB);
  }

  const float4v zz = {0.f, 0.f, 0.f, 0.f};
  float4v oaccA[4] = {zz, zz, zz, zz};
  float4v oaccB[4] = {zz, zz, zz, zz};
  float lsumA = 0.f, lsumB = 0.f;

  // prefetch chunk 0 of this half
  const int kb0 = hf * 1024;
  short8 gk0 = *(const short8*)(kh + (size_t)(kb0 + srow) * D_ + scol);
  short8 gk1 = *(const short8*)(kh + (size_t)(kb0 + srow) * D_ + scol + 32);
  short8 gv0 = *(const short8*)(vh + (size_t)srow * S_ + kb0 + scol);
  short8 gv1 = *(const short8*)(vh + (size_t)srow * S_ + kb0 + scol + 32);

  int p = 0;
  for (int c = 0; c < 16; ++c) {
    // store staged regs into buf[p] (nobody reads buf[p] right now)
    *(short8*)&smem[p][koff + srow * KP + scol] = gk0;
    *(short8*)&smem[p][koff + srow * KP + scol + 32] = gk1;
    *(short8*)&smem[p][voff + srow * KP + scol] = gv0;
    *(short8*)&smem[p][voff + srow * KP + scol + 32] = gv1;
    __syncthreads();  // buf[p] visible; prior chunk's frag reads all done
    if (c < 15) {     // prefetch next chunk during compute
      const int kb = hf * 1024 + (c + 1) * 64;
      gk0 = *(const short8*)(kh + (size_t)(kb + srow) * D_ + scol);
      gk1 = *(const short8*)(kh + (size_t)(kb + srow) * D_ + scol + 32);
      gv0 = *(const short8*)(vh + (size_t)srow * S_ + kb + scol);
      gv1 = *(const short8*)(vh + (size_t)srow * S_ + kb + scol + 32);
    }
    const __hip_bfloat16* kb_ = &smem[p][koff];
    const __hip_bfloat16* vb_ = &smem[p][voff];
#pragma unroll
    for (int t = 0; t < 4; ++t) {  // 16-key tile
      const short8 ak0 = *(const short8*)&kb_[(t * 16 + l15) * KP + l4 * 8];
      const short8 ak1 = *(const short8*)&kb_[(t * 16 + l15) * KP + 32 + l4 * 8];
      float4v cA = zz, cB = zz;
      cA = mfma32(ak0, bqA0, cA);
      cA = mfma32(ak1, bqA1, cA);
      cB = mfma32(ak0, bqB0, cB);
      cB = mfma32(ak1, bqB1, cB);
      // exp -> P in C-layout (row=key-local l4*4+r, col=query l15)
      // == B-operand layout of 16x16x16 MFMA (k=l4*4+i, n=l15): direct feed.
      short4v pA, pB;
#pragma unroll
      for (int r = 0; r < 4; ++r) {
        const float eA = __expf(cA[r]); lsumA += eA; pA[r] = f2bs(eA);
        const float eB = __expf(cB[r]); lsumB += eB; pB[r] = f2bs(eB);
      }
#pragma unroll
      for (int dt = 0; dt < 4; ++dt) {
        const short4v av = *(const short4v*)&vb_[(dt * 16 + l15) * KP + t * 16 + l4 * 4];
        oaccA[dt] = mfma16(av, pA, oaccA[dt]);
        oaccB[dt] = mfma16(av, pB, oaccB[dt]);
      }
    }
    p ^= 1;
  }
  // ---- epilogue: reduce l over quads, merge key-halves via LDS overlay ----
  float lA = lsumA + __shfl_xor(lsumA, 16); lA += __shfl_xor(lA, 32);
  float lB = lsumB + __shfl_xor(lsumB, 16); lB += __shfl_xor(lB, 32);
  __syncthreads();
  float* mbuf = (float*)&smem[0][0];          // [128][68]
  float* mlb = (float*)&smem[0][0] + 128 * 68;  // [128]
  if (hf == 1) {
#pragma unroll
    for (int dt = 0; dt < 4; ++dt)
#pragma unroll
      for (int r = 0; r < 4; ++r) {
        mbuf[qlA * 68 + dt * 16 + l4 * 4 + r] = oaccA[dt][r];
        mbuf[qlB * 68 + dt * 16 + l4 * 4 + r] = oaccB[dt][r];
      }
    if (l4 == 0) { mlb[qlA] = lA; mlb[qlB] = lB; }
  }
  __syncthreads();
  if (hf == 0) {
    const float liA = 1.f / (lA + mlb[qlA]);
    const float liB = 1.f / (lB + mlb[qlB]);
#pragma unroll
    for (int dt = 0; dt < 4; ++dt) {
      const float4v pa = *(const float4v*)&mbuf[qlA * 68 + dt * 16 + l4 * 4];
      const float4v pb = *(const float4v*)&mbuf[qlB * 68 + dt * 16 + l4 * 4];
      float4v va, vb;
#pragma unroll
      for (int r = 0; r < 4; ++r) {
        va[r] = (oaccA[dt][r] + pa[r]) * liA;
        vb[r] = (oaccB[dt][r] + pb[r]) * liB;
      }
      *(float4v*)(out + (size_t)(b * S_ + qrA) * D_ + h * HD_ + dt * 16 + l4 * 4) = va;
      *(float4v*)(out + (size_t)(b * S_ + qrB) * D_ + h * HD_ + dt * 16 + l4 * 4) = vb;
    }
  }
}

extern "C" void kernel_launch(void* const* d_in, const int* in_sizes, int n_in,
                              void* d_out, int out_size, void* d_ws, size_t ws_size,
                              hipStream_t stream) {
  const float* hs = (const float*)d_in[0];
  const int* mask = (const int*)d_in[1];
  const float* Wq = (const float*)d_in[2];
  const float* bq = (const float*)d_in[3];
  const float* Wk = (const float*)d_in[4];
  const float* bk = (const float*)d_in[5];
  float* out = (float*)d_out;
  char* ws = (char*)d_ws;
  const size_t MB = 1u << 20;
  __hip_bfloat16* q_b = (__hip_bfloat16*)(ws + 0 * MB);   // [B,S,D] bf16, 8MB
  __hip_bfloat16* k_b = (__hip_bfloat16*)(ws + 8 * MB);   // k then softplus(k), 8MB
  __hip_bfloat16* hsb = (__hip_bfloat16*)(ws + 16 * MB);  // hs bf16; later reused as vT
  __hip_bfloat16* vT  = (__hip_bfloat16*)(ws + 16 * MB);  // [B,H,HD,S] 8MB (aliases hsb)
  __hip_bfloat16* Wqt = (__hip_bfloat16*)(ws + 24 * MB);  // 2MB
  __hip_bfloat16* Wkt = (__hip_bfloat16*)(ws + 26 * MB);  // 2MB

  pre<<<dim3(16, 16, 3), 256, 0, stream>>>(Wq, Wk, hs, Wqt, Wkt, hsb);
  gemm_qk<<<dim3(8, 32, 2), 256, 0, stream>>>(hsb, Wqt, Wkt, bq, bk, q_b, k_b);
  prep<<<dim3(32, 16, 2), 256, 0, stream>>>(q_b, k_b, vT);  // overwrites hsb (done with it)
  attn<<<dim3(16, 16, 2), 512, 0, stream>>>(q_b, k_b, vT, mask, out);
}

// Round 10
// 178.948 us; speedup vs baseline: 2.7061x; 1.0903x over previous
//
#include <hip/hip_runtime.h>
#include <hip/hip_bf16.h>

#define B_ 2
#define S_ 2048
#define D_ 1024
#define H_ 16
#define HD_ 64

typedef __attribute__((ext_vector_type(8))) short short8;
typedef __attribute__((ext_vector_type(4))) short short4v;
typedef __attribute__((ext_vector_type(4))) float float4v;

typedef const __attribute__((address_space(1))) void* gas_ptr;
typedef __attribute__((address_space(3))) void* las_ptr;

static __device__ inline void gl_lds16(const void* g, void* l) {
  // async global->LDS, 16B/lane, LDS dest = wave-uniform base + lane*16
  __builtin_amdgcn_global_load_lds((gas_ptr)g, (las_ptr)l, 16, 0, 0);
}

static __device__ inline float b2f(__hip_bfloat16 h) { return __bfloat162float(h); }

static __device__ inline short f2bs(float x) {
  __hip_bfloat16 h = __float2bfloat16(x);
  union { __hip_bfloat16 h; short s; } u; u.h = h; return u.s;
}
static __device__ inline float bs2f(short s) {
  union { short s; __hip_bfloat16 h; } u; u.s = s; return __bfloat162float(u.h);
}

static __device__ inline float4v mfma32(short8 a, short8 b, float4v c) {
  return __builtin_amdgcn_mfma_f32_16x16x32_bf16(a, b, c, 0, 0, 0);
}
// v_mfma_f32_16x16x16_bf16 (4xbf16 A/B operands) — "_1k" builtin, present on gfx950.
static __device__ inline float4v mfma16(short4v a, short4v b, float4v c) {
  return __builtin_amdgcn_mfma_f32_16x16x16bf16_1k(a, b, c, 0, 0, 0);
}

// ------- Stage A (fused): z<2 -> W transpose fp32->bf16; z==2 -> hs cvt -------
__global__ __launch_bounds__(256) void pre(
    const float* __restrict__ Wq, const float* __restrict__ Wk,
    const float* __restrict__ hs,
    __hip_bfloat16* __restrict__ Wqt, __hip_bfloat16* __restrict__ Wkt,
    __hip_bfloat16* __restrict__ hsb) {
  if (blockIdx.z == 2) {
    const int blk = blockIdx.y * 16 + blockIdx.x;
    for (int it = 0; it < 8; ++it) {
      const size_t i = (size_t)blk * 16384 + it * 2048 + threadIdx.x * 8;
      const float4v v0 = *(const float4v*)(hs + i);
      const float4v v1 = *(const float4v*)(hs + i + 4);
      short8 s;
      for (int j = 0; j < 4; ++j) { s[j] = f2bs(v0[j]); s[4 + j] = f2bs(v1[j]); }
      *(short8*)(hsb + i) = s;
    }
    return;
  }
  const float* W = blockIdx.z ? Wk : Wq;
  __hip_bfloat16* Wt = blockIdx.z ? Wkt : Wqt;
  __shared__ float t[64][65];
  const int n0 = blockIdx.x * 64, k0 = blockIdx.y * 64;
  const int c = threadIdx.x & 63, r0 = threadIdx.x >> 6;
  for (int i = 0; i < 16; ++i) {
    const int r = i * 4 + r0;
    t[c][r] = W[(size_t)(k0 + r) * D_ + n0 + c];
  }
  __syncthreads();
  for (int i = 0; i < 16; ++i) {
    const int rr = i * 4 + r0;
    Wt[(size_t)(n0 + rr) * D_ + k0 + c] = __float2bfloat16(t[rr][c]);
  }
}

// ---- Stage B (fused GEMM+prep): per block computes q-tile AND k-tile of the
// same 64x128 range (A staged once), then the epilogue directly emits
// q (bf16), kt = softplus(k) (bf16), and vT[b,h,d,s] = q+k (bf16, in-register
// transpose: each lane owns 4 consecutive s -> aligned 8B stores).
// global_load_lds width-16 staging, LDS double buffer, single barrier/iter.
__global__ __launch_bounds__(256) void gemm_fused(
    const __hip_bfloat16* __restrict__ A,
    const __hip_bfloat16* __restrict__ Wqt, const __hip_bfloat16* __restrict__ Wkt,
    const float* __restrict__ bq, const float* __restrict__ bk,
    __hip_bfloat16* __restrict__ q_out, __hip_bfloat16* __restrict__ kt_out,
    __hip_bfloat16* __restrict__ vT) {
  const int n0 = blockIdx.x * 128, m0 = blockIdx.y * 64;
  __shared__ __hip_bfloat16 As[2][64 * 32];    // [m][k] rows of 32
  __shared__ __hip_bfloat16 Bq[2][128 * 32];   // [n][k]
  __shared__ __hip_bfloat16 Bk[2][128 * 32];
  const int tid = threadIdx.x, wid = tid >> 6, lane = tid & 63;
  const int wm = (wid >> 1) * 32, wn = (wid & 1) * 64;
  const int l15 = lane & 15, l4 = lane >> 4;
  const float4v zz = {0.f, 0.f, 0.f, 0.f};
  float4v accq[2][4], acck[2][4];
  for (int i = 0; i < 2; ++i)
    for (int j = 0; j < 4; ++j) { accq[i][j] = zz; acck[i][j] = zz; }
  // staging maps (contiguous lane order, gl_lds requirement):
  const int arow = wid * 16 + (lane >> 2);   // As: wave wid -> rows [16w,16w+16)
  const int brow = wid * 32 + (lane >> 2);   // Bq/Bk: rows [32w,32w+16) and +16
  const int lk8 = (lane & 3) * 8;
  // preload chunk 0 into buffer 0
  gl_lds16(A + (size_t)(m0 + arow) * D_ + lk8, As[0] + wid * 512);
  gl_lds16(Wqt + (size_t)(n0 + brow) * D_ + lk8, Bq[0] + wid * 1024);
  gl_lds16(Wqt + (size_t)(n0 + brow + 16) * D_ + lk8, Bq[0] + wid * 1024 + 512);
  gl_lds16(Wkt + (size_t)(n0 + brow) * D_ + lk8, Bk[0] + wid * 1024);
  gl_lds16(Wkt + (size_t)(n0 + brow + 16) * D_ + lk8, Bk[0] + wid * 1024 + 512);
  int p = 0;
  for (int kb = 0; kb < 32; ++kb) {
    __syncthreads();  // buf[p] staged (vmcnt drained); prev frag reads done
    if (kb < 31) {    // async loads into buf[p^1], in flight across compute
      const int kc = (kb + 1) * 32 + lk8;
      gl_lds16(A + (size_t)(m0 + arow) * D_ + kc, As[p ^ 1] + wid * 512);
      gl_lds16(Wqt + (size_t)(n0 + brow) * D_ + kc, Bq[p ^ 1] + wid * 1024);
      gl_lds16(Wqt + (size_t)(n0 + brow + 16) * D_ + kc, Bq[p ^ 1] + wid * 1024 + 512);
      gl_lds16(Wkt + (size_t)(n0 + brow) * D_ + kc, Bk[p ^ 1] + wid * 1024);
      gl_lds16(Wkt + (size_t)(n0 + brow + 16) * D_ + kc, Bk[p ^ 1] + wid * 1024 + 512);
    }
    short8 af[2], bfq[4], bfk[4];
    const int fo = l4 * 8;
    for (int rt = 0; rt < 2; ++rt)
      af[rt] = *(const short8*)(As[p] + (wm + rt * 16 + l15) * 32 + fo);
    for (int ct = 0; ct < 4; ++ct) {
      bfq[ct] = *(const short8*)(Bq[p] + (wn + ct * 16 + l15) * 32 + fo);
      bfk[ct] = *(const short8*)(Bk[p] + (wn + ct * 16 + l15) * 32 + fo);
    }
    for (int rt = 0; rt < 2; ++rt)
      for (int ct = 0; ct < 4; ++ct) {
        accq[rt][ct] = mfma32(af[rt], bfq[ct], accq[rt][ct]);
        acck[rt][ct] = mfma32(af[rt], bfk[ct], acck[rt][ct]);
      }
    p ^= 1;
  }
  // ---- epilogue: bias, softplus, v=q+k (fp32), transposed vT stores ----
  float bvq[4], bvk[4];
  for (int ct = 0; ct < 4; ++ct) {
    bvq[ct] = bq[n0 + wn + ct * 16 + l15];
    bvk[ct] = bk[n0 + wn + ct * 16 + l15];
  }
  for (int rt = 0; rt < 2; ++rt)
    for (int ct = 0; ct < 4; ++ct) {
      const int col = n0 + wn + ct * 16 + l15;
      const int h = col >> 6, d = col & 63;
      const int rowb = m0 + wm + rt * 16 + l4 * 4;
      short4v vv;
      for (int r = 0; r < 4; ++r) {
        const int row = rowb + r;
        const float qv = accq[rt][ct][r] + bvq[ct];
        const float kv = acck[rt][ct][r] + bvk[ct];
        const float sp = fmaxf(kv, 0.f) + __logf(1.f + __expf(-fabsf(kv)));
        q_out[(size_t)row * D_ + col] = __float2bfloat16(qv);
        kt_out[(size_t)row * D_ + col] = __float2bfloat16(sp);
        vv[r] = f2bs(qv + kv);
      }
      const int b = rowb >> 11, s = rowb & 2047;  // 64-row tile never crosses b
      *(short4v*)(vT + ((size_t)(b * H_ + h) * HD_ + d) * S_ + s) = vv;
    }
}

// ------- Stage D: flash attention, 2-way key split, 128 q/block, dbuf -------
#define KP 72  // row pad: 144 B, 16B-aligned rows
__global__ __launch_bounds__(512, 4) void attn(
    const __hip_bfloat16* __restrict__ qb, const __hip_bfloat16* __restrict__ ktb,
    const __hip_bfloat16* __restrict__ vT, const int* __restrict__ mask,
    float* __restrict__ out) {
  __shared__ __hip_bfloat16 smem[2][4 * 64 * KP];  // [buf][ kts[2][64][KP] ++ vts[2][64][KP] ]
  const int q0 = blockIdx.x * 128, h = blockIdx.y, b = blockIdx.z;
  const int tid = threadIdx.x, wid = tid >> 6, lane = tid & 63;
  const int l15 = lane & 15, l4 = lane >> 4;
  const int hf = wid >> 2, qt = wid & 3;
  const __hip_bfloat16* qh = qb + (size_t)b * S_ * D_ + h * HD_;
  const __hip_bfloat16* kh = ktb + (size_t)b * S_ * D_ + h * HD_;
  const __hip_bfloat16* vh = vT + (size_t)(b * H_ + h) * HD_ * S_;
  const int srow = (tid & 255) >> 2;
  const int scol = (tid & 3) * 8;
  const int koff = hf * 64 * KP;
  const int voff = (2 + hf) * 64 * KP;

  const int qlA = qt * 32 + l15, qlB = qlA + 16;
  const int qrA = q0 + qlA, qrB = q0 + qlB;
  const float mqA = (mask[b * S_ + qrA] != 0) ? 0.125f : 0.f;
  const float mqB = (mask[b * S_ + qrB] != 0) ? 0.125f : 0.f;
  const short8 rA0 = *(const short8*)(qh + (size_t)qrA * D_ + l4 * 8);
  const short8 rA1 = *(const short8*)(qh + (size_t)qrA * D_ + 32 + l4 * 8);
  const short8 rB0 = *(const short8*)(qh + (size_t)qrB * D_ + l4 * 8);
  const short8 rB1 = *(const short8*)(qh + (size_t)qrB * D_ + 32 + l4 * 8);
  short8 bqA0, bqA1, bqB0, bqB1;
  for (int j = 0; j < 8; ++j) {
    bqA0[j] = f2bs(bs2f(rA0[j]) * mqA);
    bqA1[j] = f2bs(bs2f(rA1[j]) * mqA);
    bqB0[j] = f2bs(bs2f(rB0[j]) * mqB);
    bqB1[j] = f2bs(bs2f(rB1[j]) * mqB);
  }

  const float4v zz = {0.f, 0.f, 0.f, 0.f};
  float4v oaccA[4] = {zz, zz, zz, zz};
  float4v oaccB[4] = {zz, zz, zz, zz};
  float lsumA = 0.f, lsumB = 0.f;

  const int kb0 = hf * 1024;
  short8 gk0 = *(const short8*)(kh + (size_t)(kb0 + srow) * D_ + scol);
  short8 gk1 = *(const short8*)(kh + (size_t)(kb0 + srow) * D_ + scol + 32);
  short8 gv0 = *(const short8*)(vh + (size_t)srow * S_ + kb0 + scol);
  short8 gv1 = *(const short8*)(vh + (size_t)srow * S_ + kb0 + scol + 32);

  int p = 0;
  for (int c = 0; c < 16; ++c) {
    *(short8*)&smem[p][koff + srow * KP + scol] = gk0;
    *(short8*)&smem[p][koff + srow * KP + scol + 32] = gk1;
    *(short8*)&smem[p][voff + srow * KP + scol] = gv0;
    *(short8*)&smem[p][voff + srow * KP + scol + 32] = gv1;
    __syncthreads();
    if (c < 15) {
      const int kb = hf * 1024 + (c + 1) * 64;
      gk0 = *(const short8*)(kh + (size_t)(kb + srow) * D_ + scol);
      gk1 = *(const short8*)(kh + (size_t)(kb + srow) * D_ + scol + 32);
      gv0 = *(const short8*)(vh + (size_t)srow * S_ + kb + scol);
      gv1 = *(const short8*)(vh + (size_t)srow * S_ + kb + scol + 32);
    }
    const __hip_bfloat16* kb_ = &smem[p][koff];
    const __hip_bfloat16* vb_ = &smem[p][voff];
#pragma unroll
    for (int t = 0; t < 4; ++t) {
      const short8 ak0 = *(const short8*)&kb_[(t * 16 + l15) * KP + l4 * 8];
      const short8 ak1 = *(const short8*)&kb_[(t * 16 + l15) * KP + 32 + l4 * 8];
      float4v cA = zz, cB = zz;
      cA = mfma32(ak0, bqA0, cA);
      cA = mfma32(ak1, bqA1, cA);
      cB = mfma32(ak0, bqB0, cB);
      cB = mfma32(ak1, bqB1, cB);
      short4v pA, pB;
#pragma unroll
      for (int r = 0; r < 4; ++r) {
        const float eA = __expf(cA[r]); lsumA += eA; pA[r] = f2bs(eA);
        const float eB = __expf(cB[r]); lsumB += eB; pB[r] = f2bs(eB);
      }
#pragma unroll
      for (int dt = 0; dt < 4; ++dt) {
        const short4v av = *(const short4v*)&vb_[(dt * 16 + l15) * KP + t * 16 + l4 * 4];
        oaccA[dt] = mfma16(av, pA, oaccA[dt]);
        oaccB[dt] = mfma16(av, pB, oaccB[dt]);
      }
    }
    p ^= 1;
  }
  float lA = lsumA + __shfl_xor(lsumA, 16); lA += __shfl_xor(lA, 32);
  float lB = lsumB + __shfl_xor(lsumB, 16); lB += __shfl_xor(lB, 32);
  __syncthreads();
  float* mbuf = (float*)&smem[0][0];            // [128][68]
  float* mlb = (float*)&smem[0][0] + 128 * 68;  // [128]
  if (hf == 1) {
#pragma unroll
    for (int dt = 0; dt < 4; ++dt)
#pragma unroll
      for (int r = 0; r < 4; ++r) {
        mbuf[qlA * 68 + dt * 16 + l4 * 4 + r] = oaccA[dt][r];
        mbuf[qlB * 68 + dt * 16 + l4 * 4 + r] = oaccB[dt][r];
      }
    if (l4 == 0) { mlb[qlA] = lA; mlb[qlB] = lB; }
  }
  __syncthreads();
  if (hf == 0) {
    const float liA = 1.f / (lA + mlb[qlA]);
    const float liB = 1.f / (lB + mlb[qlB]);
#pragma unroll
    for (int dt = 0; dt < 4; ++dt) {
      const float4v pa = *(const float4v*)&mbuf[qlA * 68 + dt * 16 + l4 * 4];
      const float4v pb = *(const float4v*)&mbuf[qlB * 68 + dt * 16 + l4 * 4];
      float4v va, vb;
#pragma unroll
      for (int r = 0; r < 4; ++r) {
        va[r] = (oaccA[dt][r] + pa[r]) * liA;
        vb[r] = (oaccB[dt][r] + pb[r]) * liB;
      }
      *(float4v*)(out + (size_t)(b * S_ + qrA) * D_ + h * HD_ + dt * 16 + l4 * 4) = va;
      *(float4v*)(out + (size_t)(b * S_ + qrB) * D_ + h * HD_ + dt * 16 + l4 * 4) = vb;
    }
  }
}

extern "C" void kernel_launch(void* const* d_in, const int* in_sizes, int n_in,
                              void* d_out, int out_size, void* d_ws, size_t ws_size,
                              hipStream_t stream) {
  const float* hs = (const float*)d_in[0];
  const int* mask = (const int*)d_in[1];
  const float* Wq = (const float*)d_in[2];
  const float* bq = (const float*)d_in[3];
  const float* Wk = (const float*)d_in[4];
  const float* bk = (const float*)d_in[5];
  float* out = (float*)d_out;
  char* ws = (char*)d_ws;
  const size_t MB = 1u << 20;
  __hip_bfloat16* q_b = (__hip_bfloat16*)(ws + 0 * MB);   // [B,S,D] bf16, 8MB
  __hip_bfloat16* k_b = (__hip_bfloat16*)(ws + 8 * MB);   // softplus(k), 8MB
  __hip_bfloat16* hsb = (__hip_bfloat16*)(ws + 16 * MB);  // hs bf16, 8MB
  __hip_bfloat16* vT  = (__hip_bfloat16*)(ws + 24 * MB);  // [B,H,HD,S] 8MB (distinct: gemm reads hsb while writing vT)
  __hip_bfloat16* Wqt = (__hip_bfloat16*)(ws + 32 * MB);  // 2MB
  __hip_bfloat16* Wkt = (__hip_bfloat16*)(ws + 34 * MB);  // 2MB

  pre<<<dim3(16, 16, 3), 256, 0, stream>>>(Wq, Wk, hs, Wqt, Wkt, hsb);
  gemm_fused<<<dim3(8, 64), 256, 0, stream>>>(hsb, Wqt, Wkt, bq, bk, q_b, k_b, vT);
  attn<<<dim3(16, 16, 2), 512, 0, stream>>>(q_b, k_b, vT, mask, out);
}